// Round 6
// baseline (1772.280 us; speedup 1.0000x reference)
//
#include <hip/hip_runtime.h>
#include <math.h>

constexpr int BN = 64;
constexpr int CC = 128;
constexpr int LL = 400;
constexpr int DK = 16;
constexpr int KK = 7;
constexpr int CL = CC * LL;              // 51200
constexpr int NBCL = BN * CL;            // 3276800
constexpr float EPSV = 1e-5f;
constexpr float INV_N = 1.0f / (float)CL;
constexpr float BIGL = 1.4427e30f;
constexpr int NBLK = 448;                // persistent grid (7 x 64)

typedef __attribute__((ext_vector_type(8))) short bf16x8;
typedef __attribute__((ext_vector_type(4))) float f32x4;

#if defined(__has_builtin)
#if __has_builtin(__builtin_amdgcn_exp2f)
#define EXP2F(x) __builtin_amdgcn_exp2f(x)
#endif
#endif
#ifndef EXP2F
#define EXP2F(x) exp2f(x)
#endif

__device__ __forceinline__ short f2bf(float f) {        // RNE
  unsigned u = __builtin_bit_cast(unsigned, f);
  u = (u + 0x7fffu + ((u >> 16) & 1u)) >> 16;
  return (short)u;
}
__device__ __forceinline__ float bf2f(unsigned short u) {
  return __builtin_bit_cast(float, (unsigned)u << 16);
}
__device__ __forceinline__ unsigned pkbf(float hi, float lo) {  // truncate-pack
  return __builtin_amdgcn_perm(__builtin_bit_cast(unsigned, hi),
                               __builtin_bit_cast(unsigned, lo), 0x07060302u);
}

// ---------------------------------------------------------------------------
// Manual grid barrier (no cooperative API; graph-capture safe).
// Co-residency guaranteed: 448 blocks, launch_bounds(512,4) -> 2 blocks/CU
// x 256 CU = 512 slots. Each slot used exactly once per launch; slots are
// zeroed by hipMemsetAsync before the kernel. Agent-scope fences handle
// cross-XCD L2 (Guideline 16).
// ---------------------------------------------------------------------------
__device__ __forceinline__ void gbarrier(int* bar, int slot) {
  __syncthreads();                 // drains vmcnt/lgkmcnt before barrier
  __threadfence();                 // agent-scope release (L2 writeback)
  if (threadIdx.x == 0) {
    int* p = bar + slot * 32;      // cacheline-padded slot
    __hip_atomic_fetch_add(p, 1, __ATOMIC_ACQ_REL, __HIP_MEMORY_SCOPE_AGENT);
    while (__hip_atomic_load(p, __ATOMIC_ACQUIRE, __HIP_MEMORY_SCOPE_AGENT) < NBLK) {
      __builtin_amdgcn_s_sleep(16);
    }
  }
  __syncthreads();
  __threadfence();                 // agent-scope acquire (L1/L2 invalidate)
}

// ---------------------------------------------------------------------------
// X staging (bf16 inputs) into fragment-ordered LDS tile, 8-wide groups.
// XMODE 0: + LN; XMODE 1: direct copy; XMODE 2: + LN + conv7
// ---------------------------------------------------------------------------
template<int XMODE>
__device__ __forceinline__ void stage_x(
    short* __restrict__ XsF, const unsigned short* __restrict__ Xb,
    int j0, const float* __restrict__ lng, const float* __restrict__ lnb,
    const float* __restrict__ dww, float mu, float rstd, int tid)
{
  for (int idx = tid; idx < 1024; idx += 512) {
    int c = idx >> 3;
    int l8 = (idx & 7) * 8;
    int col0 = j0 + l8;
    short hv[8];
    if (XMODE == 2) {
      const unsigned short* rp = Xb + c * LL;
      const float* gp = lng + c * LL;
      const float* bp = lnb + c * LL;
      float xn[16];
      #pragma unroll
      for (int g4 = 0; g4 < 4; g4++) {
        int p0 = col0 - 4 + g4 * 4;
        int pc = p0 < 0 ? 0 : (p0 > LL - 4 ? LL - 4 : p0);
        const ushort4 rv = *reinterpret_cast<const ushort4*>(&rp[pc]);
        const float4 gv = *reinterpret_cast<const float4*>(&gp[pc]);
        const float4 bv4 = *reinterpret_cast<const float4*>(&bp[pc]);
        float rr[4] = {bf2f(rv.x), bf2f(rv.y), bf2f(rv.z), bf2f(rv.w)};
        float gg[4] = {gv.x, gv.y, gv.z, gv.w};
        float bbv[4] = {bv4.x, bv4.y, bv4.z, bv4.w};
        #pragma unroll
        for (int e = 0; e < 4; e++) {
          int p = p0 + e;
          float v = (rr[e] - mu) * rstd * gg[e] + bbv[e];
          xn[g4 * 4 + e] = (p >= 0 && p < LL) ? v : 0.f;
        }
      }
      float w7[KK];
      #pragma unroll
      for (int j = 0; j < KK; j++) w7[j] = dww[c * KK + j];
      #pragma unroll
      for (int e = 0; e < 8; e++) {
        float a = 0.f;
        #pragma unroll
        for (int jj = 0; jj < KK; jj++) a += w7[jj] * xn[e + jj + 1];
        hv[e] = f2bf(a);
      }
    } else {
      bool valid = col0 < LL;               // LL % 8 == 0: all-or-nothing
      int col0c = valid ? col0 : 0;
      const unsigned short* xp = Xb + c * LL + col0c;
      const ushort4 u0 = *reinterpret_cast<const ushort4*>(&xp[0]);
      const ushort4 u1 = *reinterpret_cast<const ushort4*>(&xp[4]);
      unsigned short uu[8] = {u0.x, u0.y, u0.z, u0.w, u1.x, u1.y, u1.z, u1.w};
      if (XMODE == 1) {
        #pragma unroll
        for (int e = 0; e < 8; e++) hv[e] = valid ? (short)uu[e] : (short)0;
      } else {
        const float* gp = lng + c * LL + col0c;
        const float* bp = lnb + c * LL + col0c;
        const float4 g0 = *reinterpret_cast<const float4*>(&gp[0]);
        const float4 g1 = *reinterpret_cast<const float4*>(&gp[4]);
        const float4 b0 = *reinterpret_cast<const float4*>(&bp[0]);
        const float4 b1 = *reinterpret_cast<const float4*>(&bp[4]);
        float gg[8] = {g0.x, g0.y, g0.z, g0.w, g1.x, g1.y, g1.z, g1.w};
        float bbv[8] = {b0.x, b0.y, b0.z, b0.w, b1.x, b1.y, b1.z, b1.w};
        #pragma unroll
        for (int e = 0; e < 8; e++) {
          float v = (bf2f(uu[e]) - mu) * rstd * gg[e] + bbv[e];
          hv[e] = valid ? f2bf(v) : (short)0;
        }
      }
    }
    int t = (l8 >> 4) * 4 + (c >> 5);
    int quad = (c >> 3) & 3;
    int j = c & 7;
    int base = t * 512 + quad * 128 + j;
    int colb = l8 & 15;
    #pragma unroll
    for (int e = 0; e < 8; e++) XsF[base + (colb + e) * 8] = hv[e];
  }
}

// ---------------------------------------------------------------------------
// GEMM phase (shared buffers passed in so one LDS block serves all phases).
// OMODE 0: fp32 linear; 1: bf16 linear; 2: bf16 transposed (b,h,l,d)
// ---------------------------------------------------------------------------
template<int XMODE, int OMODE, bool RELU, bool ADDRES, bool STATS>
__device__ __forceinline__ void gemm_body(
    short* __restrict__ XsF, float* __restrict__ red,
    const unsigned short* __restrict__ Wf, const unsigned short* __restrict__ Xv,
    const float* __restrict__ bias, const unsigned short* __restrict__ resid,
    const float* __restrict__ lng, const float* __restrict__ lnb,
    const float* __restrict__ dww,
    const float* __restrict__ statsIn, float* __restrict__ statsOut,
    void* __restrict__ Yv)
{
  int tid = threadIdx.x;
  int bb = blockIdx.y;
  int j0 = blockIdx.x * 64;
  int w = tid >> 6, lane = tid & 63;
  bf16x8 af[4];
  #pragma unroll
  for (int kt = 0; kt < 4; kt++)
    af[kt] = *reinterpret_cast<const bf16x8*>(&Wf[(w * 4 + kt) * 512 + lane * 8]);
  float mu = 0.f, rstd = 0.f;
  if (XMODE != 1) {
    float s1 = statsIn[bb * 2 + 0], s2 = statsIn[bb * 2 + 1];
    mu = s1 * INV_N;
    rstd = rsqrtf(s2 * INV_N - mu * mu + EPSV);
  }
  stage_x<XMODE>(XsF, Xv + (size_t)bb * CL, j0, lng, lnb, dww, mu, rstd, tid);
  __syncthreads();
  int col = lane & 15, quad = lane >> 4;
  f32x4 acc[4];
  #pragma unroll
  for (int lf = 0; lf < 4; lf++) acc[lf] = (f32x4){0.f, 0.f, 0.f, 0.f};
  #pragma unroll
  for (int kt = 0; kt < 4; kt++) {
    #pragma unroll
    for (int lf = 0; lf < 4; lf++) {
      bf16x8 bx = *reinterpret_cast<const bf16x8*>(&XsF[(lf * 4 + kt) * 512 + lane * 8]);
      acc[lf] = __builtin_amdgcn_mfma_f32_16x16x32_bf16(af[kt], bx, acc[lf], 0, 0, 0);
    }
  }
  int obase = w * 16;
  float bv[4];
  #pragma unroll
  for (int r = 0; r < 4; r++) bv[r] = bias[obase + quad * 4 + r];
  float lsum = 0.f, lsq = 0.f;
  #pragma unroll
  for (int lf = 0; lf < 4; lf++) {
    if (j0 + lf * 16 < LL) {
      int l = j0 + lf * 16 + col;
      if (OMODE == 2) {
        short4 hv4 = {f2bf(acc[lf][0] + bv[0]), f2bf(acc[lf][1] + bv[1]),
                      f2bf(acc[lf][2] + bv[2]), f2bf(acc[lf][3] + bv[3])};
        *reinterpret_cast<short4*>(
            &((unsigned short*)Yv)[(((size_t)bb * 8 + w) * LL + l) * 16 + quad * 4]) = hv4;
      } else {
        #pragma unroll
        for (int r = 0; r < 4; r++) {
          float v = acc[lf][r] + bv[r];
          if (RELU) v = fmaxf(v, 0.f);
          size_t oidx = (size_t)bb * CL + (size_t)(obase + quad * 4 + r) * LL + l;
          if (ADDRES) v += bf2f(resid[oidx]);
          if (OMODE == 1) {
            unsigned short hb = (unsigned short)f2bf(v);
            ((unsigned short*)Yv)[oidx] = hb;
            if (STATS) { float vf = bf2f(hb); lsum += vf; lsq += vf * vf; }
          } else {
            ((float*)Yv)[oidx] = v;
            if (STATS) { lsum += v; lsq += v * v; }
          }
        }
      }
    }
  }
  if (STATS) {
    #pragma unroll
    for (int off = 32; off > 0; off >>= 1) {
      lsum += __shfl_down(lsum, off);
      lsq  += __shfl_down(lsq, off);
    }
    if (lane == 0) { red[w * 2] = lsum; red[w * 2 + 1] = lsq; }
    __syncthreads();
    if (tid == 0) {
      float a = 0.f, b2 = 0.f;
      #pragma unroll
      for (int w2 = 0; w2 < 8; w2++) { a += red[w2 * 2]; b2 += red[w2 * 2 + 1]; }
      atomicAdd(&statsOut[bb * 2 + 0], a);
      atomicAdd(&statsOut[bb * 2 + 1], b2);
    }
  }
}

// ---------------------------------------------------------------------------
// FUSED MAIN (persistent grid (7,64) x 512, manual barriers):
//   P0 prep -> B0 -> P1 addpos(+inline pos enc)+stats0 -> B1 ->
//   P2..P5 conv layers (B2..B4 between, B5 after) -> P6 qkv
// ---------------------------------------------------------------------------
__global__ __launch_bounds__(512, 4) void fused_main(
    const float* __restrict__ pw_w, const float* __restrict__ wq,
    const float* __restrict__ wk, const float* __restrict__ wvp,
    const float* __restrict__ wo, const float* __restrict__ fcw,
    const float* __restrict__ pw_b, const float* __restrict__ dw_b,
    const float* __restrict__ mask, const float* __restrict__ x,
    const float* __restrict__ lng, const float* __restrict__ lnb,
    const float* __restrict__ dw_w,
    const float* __restrict__ bq, const float* __restrict__ bk,
    const float* __restrict__ bvp,
    unsigned short* __restrict__ wf, float* __restrict__ stats,
    float* __restrict__ beff, float* __restrict__ maddb,
    unsigned short* __restrict__ r0, unsigned short* __restrict__ r1,
    unsigned short* __restrict__ qt, unsigned short* __restrict__ kt,
    unsigned short* __restrict__ vbf, int* __restrict__ bar)
{
  __shared__ short XsF[16 * 512];
  __shared__ float red[16];
  int tid = threadIdx.x;
  int blockFlat = blockIdx.y * 7 + blockIdx.x;      // grid (7,64)
  int gtid = blockFlat * 512 + tid;

  // ---- P0: prep ----
  {
    int idx = gtid;
    if (idx < 147456) {                  // 9 x 128x128 fp32 -> bf16 frag order
      int mat = idx >> 14, e = idx & 16383;
      const float* src;
      if (mat < 4)       src = pw_w + mat * 16384;
      else if (mat == 4) src = wq;
      else if (mat == 5) src = wk;
      else if (mat == 6) src = wvp;
      else if (mat == 7) src = wo;
      else               src = fcw;
      int o = e >> 7, c = e & 127;
      int t = (o >> 4) * 4 + (c >> 5);
      int quad = (c >> 3) & 3, col = o & 15, j = c & 7;
      wf[mat * 16384 + t * 512 + (quad * 16 + col) * 8 + j] = (unsigned short)f2bf(src[e]);
    } else if (idx < 174080) {           // additive mask 64 x 416
      int i2 = idx - 147456;
      int b = i2 / 416, m = i2 - b * 416;
      maddb[i2] = (m < LL) ? (mask[b * LL + m] - 1.f) * BIGL : -BIGL;
    } else if (idx < 175104) {           // stats zero (1024 f)
      stats[idx - 174080] = 0.f;
    } else if (idx < 175616) {           // beff[i][o] = pw_b + PW @ dw_b
      int t2 = idx - 175104;
      int i2 = t2 >> 7, o = t2 & 127;
      float a = pw_b[t2];
      const float* wrow = pw_w + (size_t)i2 * 16384 + o * 128;
      const float* db = dw_b + i2 * 128;
      for (int c2 = 0; c2 < 128; c2++) a += wrow[c2] * db[c2];
      beff[t2] = a;
    }
  }
  gbarrier(bar, 0);

  // ---- P1: res(bf16) = x + pos_enc (inline), stats0 on rounded values ----
  {
    #pragma unroll 1
    for (int pass = 0; pass < 4; pass++) {
      int idx4 = pass * 229376 + gtid;           // 819200 quads total
      bool act = idx4 < 819200;                  // uniform per block (512-granular)
      float s1 = 0.f, s2 = 0.f;
      int b = 0;
      if (act) {
        b = idx4 / 12800;                        // quads per batch
        int q = idx4 - b * 12800;
        int cl4 = q * 4;
        int c = cl4 / LL;
        int l = cl4 - c * LL;                    // l..l+3 same c (4 | 400)
        float fc2 = (float)c, freq, ph;
        if ((c & 1) == 0) { freq = powf(10000.f, -fc2 / (float)CC);        ph = 0.f; }
        else              { freq = -powf(10000.f, (1.f - fc2) / (float)CC); ph = 1.5707963267948966f; }
        const float4 xv = *reinterpret_cast<const float4*>(&x[(size_t)idx4 * 4]);
        ushort4 h;
        h.x = (unsigned short)f2bf(xv.x + sinf((float)(l + 0) * freq + ph));
        h.y = (unsigned short)f2bf(xv.y + sinf((float)(l + 1) * freq + ph));
        h.z = (unsigned short)f2bf(xv.z + sinf((float)(l + 2) * freq + ph));
        h.w = (unsigned short)f2bf(xv.w + sinf((float)(l + 3) * freq + ph));
        *reinterpret_cast<ushort4*>(&r0[(size_t)idx4 * 4]) = h;
        float v0 = bf2f(h.x), v1 = bf2f(h.y), v2 = bf2f(h.z), v3 = bf2f(h.w);
        s1 = v0 + v1 + v2 + v3;
        s2 = v0 * v0 + v1 * v1 + v2 * v2 + v3 * v3;
      }
      #pragma unroll
      for (int off = 32; off > 0; off >>= 1) {
        s1 += __shfl_down(s1, off);
        s2 += __shfl_down(s2, off);
      }
      int wv = tid >> 6, lane = tid & 63;
      if (lane == 0) { red[wv * 2] = s1; red[wv * 2 + 1] = s2; }
      __syncthreads();
      if (tid == 0 && act) {                      // whole block same b
        float a = 0.f, b2 = 0.f;
        #pragma unroll
        for (int w2 = 0; w2 < 8; w2++) { a += red[w2 * 2]; b2 += red[w2 * 2 + 1]; }
        atomicAdd(&stats[b * 2 + 0], a);
        atomicAdd(&stats[b * 2 + 1], b2);
      }
      __syncthreads();                            // red WAR across passes
    }
  }
  gbarrier(bar, 1);

  // ---- P2..P5: conv layers (LN+dwconv staged, MFMA, ReLU+resid, stats) ----
  gemm_body<2, 1, true, true, true>(XsF, red, wf + 0 * 16384, r0, beff + 0 * CC,
      r0, lng, lnb, dw_w + 0 * CC * KK, stats + 0 * 128, stats + 1 * 128, r1);
  gbarrier(bar, 2);
  gemm_body<2, 1, true, true, true>(XsF, red, wf + 1 * 16384, r1, beff + 1 * CC,
      r1, lng, lnb, dw_w + 1 * CC * KK, stats + 1 * 128, stats + 2 * 128, r0);
  gbarrier(bar, 3);
  gemm_body<2, 1, true, true, true>(XsF, red, wf + 2 * 16384, r0, beff + 2 * CC,
      r0, lng, lnb, dw_w + 2 * CC * KK, stats + 2 * 128, stats + 3 * 128, r1);
  gbarrier(bar, 4);
  gemm_body<2, 1, true, true, true>(XsF, red, wf + 3 * 16384, r1, beff + 3 * CC,
      r1, lng, lnb, dw_w + 3 * CC * KK, stats + 3 * 128, stats + 4 * 128, r0);
  gbarrier(bar, 5);

  // ---- P6: QKV (one staging, 3 GEMMs) ----
  {
    int bb = blockIdx.y;
    int j0 = blockIdx.x * 64;
    int w = tid >> 6, lane = tid & 63;
    float s1 = stats[4 * 128 + bb * 2 + 0], s2 = stats[4 * 128 + bb * 2 + 1];
    float mu = s1 * INV_N;
    float rstd = rsqrtf(s2 * INV_N - mu * mu + EPSV);
    stage_x<0>(XsF, r0 + (size_t)bb * CL, j0, lng, lnb, nullptr, mu, rstd, tid);
    __syncthreads();
    int col = lane & 15, quad = lane >> 4;
    int obase = w * 16;
    #pragma unroll 1
    for (int m = 0; m < 3; m++) {
      const unsigned short* Wf = wf + (size_t)(4 + m) * 16384;
      const float* bias = (m == 0) ? bq : (m == 1) ? bk : bvp;
      bf16x8 af[4];
      #pragma unroll
      for (int kt2 = 0; kt2 < 4; kt2++)
        af[kt2] = *reinterpret_cast<const bf16x8*>(&Wf[(w * 4 + kt2) * 512 + lane * 8]);
      f32x4 acc[4];
      #pragma unroll
      for (int lf = 0; lf < 4; lf++) acc[lf] = (f32x4){0.f, 0.f, 0.f, 0.f};
      #pragma unroll
      for (int kt2 = 0; kt2 < 4; kt2++) {
        #pragma unroll
        for (int lf = 0; lf < 4; lf++) {
          bf16x8 bx = *reinterpret_cast<const bf16x8*>(&XsF[(lf * 4 + kt2) * 512 + lane * 8]);
          acc[lf] = __builtin_amdgcn_mfma_f32_16x16x32_bf16(af[kt2], bx, acc[lf], 0, 0, 0);
        }
      }
      float bv4[4];
      #pragma unroll
      for (int r = 0; r < 4; r++) bv4[r] = bias[obase + quad * 4 + r];
      if (m < 2) {
        unsigned short* dst = (m == 0) ? qt : kt;
        #pragma unroll
        for (int lf = 0; lf < 4; lf++) {
          if (j0 + lf * 16 < LL) {
            int l = j0 + lf * 16 + col;
            short4 hv4 = {f2bf(acc[lf][0] + bv4[0]), f2bf(acc[lf][1] + bv4[1]),
                          f2bf(acc[lf][2] + bv4[2]), f2bf(acc[lf][3] + bv4[3])};
            *reinterpret_cast<short4*>(
                &dst[(((size_t)bb * 8 + w) * LL + l) * 16 + quad * 4]) = hv4;
          }
        }
      } else {
        #pragma unroll
        for (int lf = 0; lf < 4; lf++) {
          if (j0 + lf * 16 < LL) {
            int l = j0 + lf * 16 + col;
            #pragma unroll
            for (int r = 0; r < 4; r++) {
              float v = acc[lf][r] + bv4[r];
              vbf[(size_t)bb * CL + (size_t)(obase + quad * 4 + r) * LL + l] =
                  (unsigned short)f2bf(v);
            }
          }
        }
      }
    }
  }
}

// ---------------------------------------------------------------------------
// WO + FC fused (persistent, barrier slot 6): wo->stats5, barrier, fc->out
// ---------------------------------------------------------------------------
__global__ __launch_bounds__(512, 4) void wo_fc_fused(
    const unsigned short* __restrict__ wf, const float* __restrict__ bo,
    const float* __restrict__ fcb, const unsigned short* __restrict__ tb,
    const unsigned short* __restrict__ r0, unsigned short* __restrict__ r1,
    const float* __restrict__ lng, const float* __restrict__ lnb,
    float* __restrict__ stats, float* __restrict__ out, int* __restrict__ bar)
{
  __shared__ short XsF[16 * 512];
  __shared__ float red[16];
  // WO projection + residual -> r1 (bf16), stats5
  gemm_body<1, 1, false, true, true>(XsF, red, wf + 7 * 16384, tb, bo, r0,
      nullptr, nullptr, nullptr, nullptr, stats + 5 * 128, r1);
  gbarrier(bar, 6);
  // FC (LN on load) + ReLU + residual -> out (fp32)
  gemm_body<0, 0, true, true, false>(XsF, red, wf + 8 * 16384, r1, fcb, r1,
      lng, lnb, nullptr, stats + 5 * 128, nullptr, out);
}

// ---------------------------------------------------------------------------
// 3) attention: 4 waves/block = 2 l-tiles x 2 m-halves (static-max softmax
//    partials combine additively). 16-row f-level double-buffered P per wave.
// ---------------------------------------------------------------------------
__global__ __launch_bounds__(256, 4) void attn_kernel(
    const unsigned short* __restrict__ qt, const unsigned short* __restrict__ kt,
    const unsigned short* __restrict__ vb, const float* __restrict__ maddb,
    unsigned short* __restrict__ ao)
{
  __shared__ short Pl[4][2][640];           // 10240 B: per-wave f-level dbuf
  __shared__ float Mg[2][64][20];           // 10240 B: merge of[16]+psum[4]
  int bh = blockIdx.x;
  int b = bh >> 3, h = bh & 7;
  int w = threadIdx.x >> 6, lane = threadIdx.x & 63;
  int pair = w >> 1, half = w & 1;
  int tile = blockIdx.y * 2 + pair;
  bool live = tile < 7;
  int tile_c = live ? tile : 6;
  int col = lane & 15, quad = lane >> 4;
  int l0 = tile_c * 64;
  size_t trow = ((size_t)b * 8 + h) * LL;
  size_t base = ((size_t)b * CC + h * DK) * LL;
  const unsigned short* qp = qt + trow * 16;
  const unsigned short* kp = kt + trow * 16;
  const unsigned short* vp = vb + base;
  const float* mb = maddb + (size_t)b * 416;

  bf16x8 qf[4];
  #pragma unroll
  for (int f = 0; f < 4; f++) {
    bf16x8 v = {};
    if (quad < 2) {
      int l = l0 + f * 16 + col; int lc = l < LL ? l : LL - 1;
      v = *reinterpret_cast<const bf16x8*>(&qp[lc * 16 + quad * 8]);
    }
    qf[f] = v;
  }
  f32x4 of[4];
  float psum[4];
  #pragma unroll
  for (int f = 0; f < 4; f++) {
    of[f] = (f32x4){0.f, 0.f, 0.f, 0.f};
    psum[f] = 0.f;
  }
  const float scale2 = 0.08838834764831845f * 1.4426950408889634f;  // /sqrt(128)*log2e

  int mstart = half ? 224 : 0;
  int mend   = half ? 416 : 224;            // 6 / 7 steps of 32
  for (int m0 = mstart; m0 < mend; m0 += 32) {
    bf16x8 kf0 = {}, kf1 = {};
    if (quad < 2) {
      int mc0 = m0 + col < LL ? m0 + col : LL - 1;
      int mc1 = m0 + 16 + col < LL ? m0 + 16 + col : LL - 1;
      kf0 = *reinterpret_cast<const bf16x8*>(&kp[mc0 * 16 + quad * 8]);
      kf1 = *reinterpret_cast<const bf16x8*>(&kp[mc1 * 16 + quad * 8]);
    }
    bf16x8 vf;
    {
      int ms = m0 + quad * 8; if (ms > LL - 8) ms = LL - 8;
      vf = *reinterpret_cast<const bf16x8*>(&vp[col * LL + ms]);
    }
    const float4 a4 = *reinterpret_cast<const float4*>(&mb[m0 + quad * 4]);
    const float4 b4 = *reinterpret_cast<const float4*>(&mb[m0 + 16 + quad * 4]);
    float madd[8] = {a4.x, a4.y, a4.z, a4.w, b4.x, b4.y, b4.z, b4.w};
    #pragma unroll
    for (int f = 0; f < 4; f++) {
      f32x4 z = {0.f, 0.f, 0.f, 0.f};
      f32x4 s0 = __builtin_amdgcn_mfma_f32_16x16x32_bf16(kf0, qf[f], z, 0, 0, 0);
      f32x4 s1 = __builtin_amdgcn_mfma_f32_16x16x32_bf16(kf1, qf[f], z, 0, 0, 0);
      float p[8];
      #pragma unroll
      for (int r = 0; r < 4; r++) {
        p[r]     = EXP2F(s0[r] * scale2 + madd[r]);
        p[4 + r] = EXP2F(s1[r] * scale2 + madd[4 + r]);
      }
      float ps = 0.f;
      #pragma unroll
      for (int i = 0; i < 8; i++) ps += p[i];
      psum[f] += ps;
      short* row = &Pl[w][f & 1][col * 40];
      short4 h0 = __builtin_bit_cast(short4, make_uint2(pkbf(p[1], p[0]), pkbf(p[3], p[2])));
      short4 h1 = __builtin_bit_cast(short4, make_uint2(pkbf(p[5], p[4]), pkbf(p[7], p[6])));
      *reinterpret_cast<short4*>(&row[quad * 4])      = h0;
      *reinterpret_cast<short4*>(&row[16 + quad * 4]) = h1;
      bf16x8 pf = *reinterpret_cast<const bf16x8*>(&Pl[w][f & 1][col * 40 + quad * 8]);
      of[f] = __builtin_amdgcn_mfma_f32_16x16x32_bf16(vf, pf, of[f], 0, 0, 0);
    }
  }
  // merge halves: half-1 waves publish partials, half-0 waves combine
  if (half == 1) {
    float* mg = &Mg[pair][lane][0];
    #pragma unroll
    for (int f = 0; f < 4; f++) {
      #pragma unroll
      for (int r = 0; r < 4; r++) mg[f * 4 + r] = of[f][r];
      mg[16 + f] = psum[f];
    }
  }
  __syncthreads();
  if (half == 0 && live) {
    const float* mg = &Mg[pair][lane][0];
    #pragma unroll
    for (int f = 0; f < 4; f++) {
      #pragma unroll
      for (int r = 0; r < 4; r++) of[f][r] += mg[f * 4 + r];
      psum[f] += mg[16 + f];
    }
    #pragma unroll
    for (int f = 0; f < 4; f++) {
      float s = psum[f];
      s += __shfl_xor(s, 16);
      s += __shfl_xor(s, 32);
      float inv = 1.f / s;
      int lf = l0 + f * 16;
      if (lf < LL) {
        #pragma unroll
        for (int r = 0; r < 4; r++)
          ao[base + (size_t)(quad * 4 + r) * LL + lf + col] =
              (unsigned short)f2bf(of[f][r] * inv);
      }
    }
  }
}

// ---------------------------------------------------------------------------
extern "C" void kernel_launch(void* const* d_in, const int* in_sizes, int n_in,
                              void* d_out, int out_size, void* d_ws, size_t ws_size,
                              hipStream_t stream) {
  const float* x    = (const float*)d_in[0];
  const float* mask = (const float*)d_in[1];
  const float* dw_w = (const float*)d_in[2];
  const float* dw_b = (const float*)d_in[3];
  const float* pw_w = (const float*)d_in[4];
  const float* pw_b = (const float*)d_in[5];
  const float* wq   = (const float*)d_in[6];
  const float* bq   = (const float*)d_in[7];
  const float* wk   = (const float*)d_in[8];
  const float* bk   = (const float*)d_in[9];
  const float* wvp  = (const float*)d_in[10];
  const float* bv   = (const float*)d_in[11];
  const float* wo   = (const float*)d_in[12];
  const float* bo   = (const float*)d_in[13];
  const float* fcw  = (const float*)d_in[14];
  const float* fcb  = (const float*)d_in[15];
  const float* lng  = (const float*)d_in[16];
  const float* lnb  = (const float*)d_in[17];
  float* out = (float*)d_out;
  float* ws  = (float*)d_ws;

  float* stats = ws;                                    // 1024 f
  float* pose  = ws + 1024;                             // 51200 f (unused)
  float* beff  = pose + 51200;                          // 512 f
  float* maddb = beff + 512;                            // 64*416 f
  unsigned short* wf = (unsigned short*)(maddb + 64 * 416); // 9*16384 bf16
  unsigned short* r0 = wf + 9 * 16384;                  // NBCL bf16 each:
  unsigned short* r1 = r0 + NBCL;
  unsigned short* qt = r1 + NBCL;
  unsigned short* kt = qt + NBCL;
  unsigned short* vbf = kt + NBCL;
  unsigned short* tb = vbf + NBCL;
  int* bar = (int*)(tb + NBCL);                         // 8 slots x 32 ints

  hipMemsetAsync(bar, 0, 8 * 32 * sizeof(int), stream); // zero barrier slots

  fused_main<<<dim3(7, BN), 512, 0, stream>>>(
      pw_w, wq, wk, wvp, wo, fcw, pw_b, dw_b, mask, x, lng, lnb, dw_w,
      bq, bk, bv, wf, stats, beff, maddb, r0, r1, qt, kt, vbf, bar);
  attn_kernel<<<dim3(512, 4), 256, 0, stream>>>(qt, kt, vbf, maddb, tb);
  wo_fc_fused<<<dim3(7, BN), 512, 0, stream>>>(
      wf, bo, fcb, tb, r0, r1, lng, lnb, stats, out, bar);
}

// Round 7
// 565.083 us; speedup vs baseline: 3.1363x; 3.1363x over previous
//
#include <hip/hip_runtime.h>
#include <math.h>

constexpr int BN = 64;
constexpr int CC = 128;
constexpr int LL = 400;
constexpr int DK = 16;
constexpr int KK = 7;
constexpr int CL = CC * LL;              // 51200
constexpr int NBCL = BN * CL;            // 3276800
constexpr float EPSV = 1e-5f;
constexpr float INV_N = 1.0f / (float)CL;
constexpr float BIGL = 1.4427e30f;
constexpr int NBLK = 448;                // persistent grid (7 x 64)
constexpr int PSTRIDE = BN * 7 * 2;      // 896 floats per stats layer

typedef __attribute__((ext_vector_type(8))) short bf16x8;
typedef __attribute__((ext_vector_type(4))) float f32x4;

#if defined(__has_builtin)
#if __has_builtin(__builtin_amdgcn_exp2f)
#define EXP2F(x) __builtin_amdgcn_exp2f(x)
#endif
#endif
#ifndef EXP2F
#define EXP2F(x) exp2f(x)
#endif

__device__ __forceinline__ short f2bf(float f) {        // RNE
  unsigned u = __builtin_bit_cast(unsigned, f);
  u = (u + 0x7fffu + ((u >> 16) & 1u)) >> 16;
  return (short)u;
}
__device__ __forceinline__ float bf2f(unsigned short u) {
  return __builtin_bit_cast(float, (unsigned)u << 16);
}
__device__ __forceinline__ unsigned pkbf(float hi, float lo) {  // truncate-pack
  return __builtin_amdgcn_perm(__builtin_bit_cast(unsigned, hi),
                               __builtin_bit_cast(unsigned, lo), 0x07060302u);
}

// ---------------------------------------------------------------------------
// Manual grid barrier, v2. Round-6 v1 cost ~200us/barrier: block-wide
// __threadfence (7168 wbl2/inv per barrier) + ACQUIRE load per poll
// (buffer_inv per iteration) = cache-invalidate storm. v2: fences from
// thread0 only (once each side), RELAXED spin loads (no per-poll inv).
// Co-residency proven in round 6 (occupancy 43% = all 3584 waves).
// ---------------------------------------------------------------------------
__device__ __forceinline__ void gbarrier(int* bar, int slot) {
  __syncthreads();                 // drains block's vmcnt (stores are in L2)
  if (threadIdx.x == 0) {
    __threadfence();               // release: one wave's wbl2 flushes L2
    int* p = bar + slot * 32;      // cacheline-padded slot
    __hip_atomic_fetch_add(p, 1, __ATOMIC_RELAXED, __HIP_MEMORY_SCOPE_AGENT);
    while (__hip_atomic_load(p, __ATOMIC_RELAXED, __HIP_MEMORY_SCOPE_AGENT) < NBLK)
      __builtin_amdgcn_s_sleep(2);
    __threadfence();               // acquire: invalidate stale L1/L2 lines
  }
  __syncthreads();                 // block shares one CU/L1: thread0's inv covers it
}

// ---------------------------------------------------------------------------
// X staging (bf16 inputs) into fragment-ordered LDS tile, 8-wide groups.
// XMODE 0: + LN; XMODE 1: direct copy; XMODE 2: + LN + conv7
// ---------------------------------------------------------------------------
template<int XMODE>
__device__ __forceinline__ void stage_x(
    short* __restrict__ XsF, const unsigned short* __restrict__ Xb,
    int j0, const float* __restrict__ lng, const float* __restrict__ lnb,
    const float* __restrict__ dww, float mu, float rstd, int tid)
{
  for (int idx = tid; idx < 1024; idx += 512) {
    int c = idx >> 3;
    int l8 = (idx & 7) * 8;
    int col0 = j0 + l8;
    short hv[8];
    if (XMODE == 2) {
      const unsigned short* rp = Xb + c * LL;
      const float* gp = lng + c * LL;
      const float* bp = lnb + c * LL;
      float xn[16];
      #pragma unroll
      for (int g4 = 0; g4 < 4; g4++) {
        int p0 = col0 - 4 + g4 * 4;
        int pc = p0 < 0 ? 0 : (p0 > LL - 4 ? LL - 4 : p0);
        const ushort4 rv = *reinterpret_cast<const ushort4*>(&rp[pc]);
        const float4 gv = *reinterpret_cast<const float4*>(&gp[pc]);
        const float4 bv4 = *reinterpret_cast<const float4*>(&bp[pc]);
        float rr[4] = {bf2f(rv.x), bf2f(rv.y), bf2f(rv.z), bf2f(rv.w)};
        float gg[4] = {gv.x, gv.y, gv.z, gv.w};
        float bbv[4] = {bv4.x, bv4.y, bv4.z, bv4.w};
        #pragma unroll
        for (int e = 0; e < 4; e++) {
          int p = p0 + e;
          float v = (rr[e] - mu) * rstd * gg[e] + bbv[e];
          xn[g4 * 4 + e] = (p >= 0 && p < LL) ? v : 0.f;
        }
      }
      float w7[KK];
      #pragma unroll
      for (int j = 0; j < KK; j++) w7[j] = dww[c * KK + j];
      #pragma unroll
      for (int e = 0; e < 8; e++) {
        float a = 0.f;
        #pragma unroll
        for (int jj = 0; jj < KK; jj++) a += w7[jj] * xn[e + jj + 1];
        hv[e] = f2bf(a);
      }
    } else {
      bool valid = col0 < LL;               // LL % 8 == 0: all-or-nothing
      int col0c = valid ? col0 : 0;
      const unsigned short* xp = Xb + c * LL + col0c;
      const ushort4 u0 = *reinterpret_cast<const ushort4*>(&xp[0]);
      const ushort4 u1 = *reinterpret_cast<const ushort4*>(&xp[4]);
      unsigned short uu[8] = {u0.x, u0.y, u0.z, u0.w, u1.x, u1.y, u1.z, u1.w};
      if (XMODE == 1) {
        #pragma unroll
        for (int e = 0; e < 8; e++) hv[e] = valid ? (short)uu[e] : (short)0;
      } else {
        const float* gp = lng + c * LL + col0c;
        const float* bp = lnb + c * LL + col0c;
        const float4 g0 = *reinterpret_cast<const float4*>(&gp[0]);
        const float4 g1 = *reinterpret_cast<const float4*>(&gp[4]);
        const float4 b0 = *reinterpret_cast<const float4*>(&bp[0]);
        const float4 b1 = *reinterpret_cast<const float4*>(&bp[4]);
        float gg[8] = {g0.x, g0.y, g0.z, g0.w, g1.x, g1.y, g1.z, g1.w};
        float bbv[8] = {b0.x, b0.y, b0.z, b0.w, b1.x, b1.y, b1.z, b1.w};
        #pragma unroll
        for (int e = 0; e < 8; e++) {
          float v = (bf2f(uu[e]) - mu) * rstd * gg[e] + bbv[e];
          hv[e] = valid ? f2bf(v) : (short)0;
        }
      }
    }
    int t = (l8 >> 4) * 4 + (c >> 5);
    int quad = (c >> 3) & 3;
    int j = c & 7;
    int base = t * 512 + quad * 128 + j;
    int colb = l8 & 15;
    #pragma unroll
    for (int e = 0; e < 8; e++) XsF[base + (colb + e) * 8] = hv[e];
  }
}

// ---------------------------------------------------------------------------
// GEMM phase. LN stats now via per-block PARTIALS (no atomics, no zeroing):
// statsIn = layer partial base (sum 7 entries per b); statsOut likewise.
// OMODE 0: fp32 linear; 1: bf16 linear; 2: bf16 transposed (b,h,l,d)
// ---------------------------------------------------------------------------
template<int XMODE, int OMODE, bool RELU, bool ADDRES, bool STATS>
__device__ __forceinline__ void gemm_body(
    short* __restrict__ XsF, float* __restrict__ red,
    const unsigned short* __restrict__ Wf, const unsigned short* __restrict__ Xv,
    const float* __restrict__ bias, const unsigned short* __restrict__ resid,
    const float* __restrict__ lng, const float* __restrict__ lnb,
    const float* __restrict__ dww,
    const float* __restrict__ statsIn, float* __restrict__ statsOut,
    void* __restrict__ Yv)
{
  int tid = threadIdx.x;
  int bb = blockIdx.y;
  int j0 = blockIdx.x * 64;
  int w = tid >> 6, lane = tid & 63;
  bf16x8 af[4];
  #pragma unroll
  for (int kt = 0; kt < 4; kt++)
    af[kt] = *reinterpret_cast<const bf16x8*>(&Wf[(w * 4 + kt) * 512 + lane * 8]);
  float mu = 0.f, rstd = 0.f;
  if (XMODE != 1) {
    float s1 = 0.f, s2 = 0.f;
    #pragma unroll
    for (int k2 = 0; k2 < 7; k2++) {
      s1 += statsIn[(bb * 7 + k2) * 2 + 0];
      s2 += statsIn[(bb * 7 + k2) * 2 + 1];
    }
    mu = s1 * INV_N;
    rstd = rsqrtf(s2 * INV_N - mu * mu + EPSV);
  }
  stage_x<XMODE>(XsF, Xv + (size_t)bb * CL, j0, lng, lnb, dww, mu, rstd, tid);
  __syncthreads();
  int col = lane & 15, quad = lane >> 4;
  f32x4 acc[4];
  #pragma unroll
  for (int lf = 0; lf < 4; lf++) acc[lf] = (f32x4){0.f, 0.f, 0.f, 0.f};
  #pragma unroll
  for (int kt = 0; kt < 4; kt++) {
    #pragma unroll
    for (int lf = 0; lf < 4; lf++) {
      bf16x8 bx = *reinterpret_cast<const bf16x8*>(&XsF[(lf * 4 + kt) * 512 + lane * 8]);
      acc[lf] = __builtin_amdgcn_mfma_f32_16x16x32_bf16(af[kt], bx, acc[lf], 0, 0, 0);
    }
  }
  int obase = w * 16;
  float bv[4];
  #pragma unroll
  for (int r = 0; r < 4; r++) bv[r] = bias[obase + quad * 4 + r];
  float lsum = 0.f, lsq = 0.f;
  #pragma unroll
  for (int lf = 0; lf < 4; lf++) {
    if (j0 + lf * 16 < LL) {
      int l = j0 + lf * 16 + col;
      if (OMODE == 2) {
        short4 hv4 = {f2bf(acc[lf][0] + bv[0]), f2bf(acc[lf][1] + bv[1]),
                      f2bf(acc[lf][2] + bv[2]), f2bf(acc[lf][3] + bv[3])};
        *reinterpret_cast<short4*>(
            &((unsigned short*)Yv)[(((size_t)bb * 8 + w) * LL + l) * 16 + quad * 4]) = hv4;
      } else {
        #pragma unroll
        for (int r = 0; r < 4; r++) {
          float v = acc[lf][r] + bv[r];
          if (RELU) v = fmaxf(v, 0.f);
          size_t oidx = (size_t)bb * CL + (size_t)(obase + quad * 4 + r) * LL + l;
          if (ADDRES) v += bf2f(resid[oidx]);
          if (OMODE == 1) {
            unsigned short hb = (unsigned short)f2bf(v);
            ((unsigned short*)Yv)[oidx] = hb;
            if (STATS) { float vf = bf2f(hb); lsum += vf; lsq += vf * vf; }
          } else {
            ((float*)Yv)[oidx] = v;
            if (STATS) { lsum += v; lsq += v * v; }
          }
        }
      }
    }
  }
  if (STATS) {
    #pragma unroll
    for (int off = 32; off > 0; off >>= 1) {
      lsum += __shfl_down(lsum, off);
      lsq  += __shfl_down(lsq, off);
    }
    if (lane == 0) { red[w * 2] = lsum; red[w * 2 + 1] = lsq; }
    __syncthreads();
    if (tid == 0) {
      float a = 0.f, b2 = 0.f;
      #pragma unroll
      for (int w2 = 0; w2 < 8; w2++) { a += red[w2 * 2]; b2 += red[w2 * 2 + 1]; }
      statsOut[(bb * 7 + blockIdx.x) * 2 + 0] = a;     // partial, no atomic
      statsOut[(bb * 7 + blockIdx.x) * 2 + 1] = b2;
    }
  }
}

// ---------------------------------------------------------------------------
// FUSED MAIN (persistent grid (7,64) x 512, manual barriers):
//   P0 prep (wf/maddb/beff)  ||  P1 addpos+inline-pos-enc -> pstat0
//   B0 -> conv1 -> B1 -> conv2 -> B2 -> conv3 -> B3 -> conv4 -> B4 -> qkv
// (P0 and P1 are independent now: partial-stats removed the stats-zero dep)
// ---------------------------------------------------------------------------
__global__ __launch_bounds__(512, 4) void fused_main(
    const float* __restrict__ pw_w, const float* __restrict__ wq,
    const float* __restrict__ wk, const float* __restrict__ wvp,
    const float* __restrict__ wo, const float* __restrict__ fcw,
    const float* __restrict__ pw_b, const float* __restrict__ dw_b,
    const float* __restrict__ mask, const float* __restrict__ x,
    const float* __restrict__ lng, const float* __restrict__ lnb,
    const float* __restrict__ dw_w,
    const float* __restrict__ bq, const float* __restrict__ bk,
    const float* __restrict__ bvp,
    unsigned short* __restrict__ wf, float* __restrict__ pstat,
    float* __restrict__ beff, float* __restrict__ maddb,
    unsigned short* __restrict__ r0, unsigned short* __restrict__ r1,
    unsigned short* __restrict__ qt, unsigned short* __restrict__ kt,
    unsigned short* __restrict__ vbf, int* __restrict__ bar)
{
  __shared__ short XsF[16 * 512];
  __shared__ float red[16];
  int tid = threadIdx.x;
  int blockFlat = blockIdx.y * 7 + blockIdx.x;      // grid (7,64)
  int gtid = blockFlat * 512 + tid;

  // ---- P0: prep (weights frag / maddb / beff) ----
  {
    int idx = gtid;
    if (idx < 147456) {                  // 9 x 128x128 fp32 -> bf16 frag order
      int mat = idx >> 14, e = idx & 16383;
      const float* src;
      if (mat < 4)       src = pw_w + mat * 16384;
      else if (mat == 4) src = wq;
      else if (mat == 5) src = wk;
      else if (mat == 6) src = wvp;
      else if (mat == 7) src = wo;
      else               src = fcw;
      int o = e >> 7, c = e & 127;
      int t = (o >> 4) * 4 + (c >> 5);
      int quad = (c >> 3) & 3, col = o & 15, j = c & 7;
      wf[mat * 16384 + t * 512 + (quad * 16 + col) * 8 + j] = (unsigned short)f2bf(src[e]);
    } else if (idx < 174080) {           // additive mask 64 x 416
      int i2 = idx - 147456;
      int b = i2 / 416, m = i2 - b * 416;
      maddb[i2] = (m < LL) ? (mask[b * LL + m] - 1.f) * BIGL : -BIGL;
    } else if (idx < 174592) {           // beff[i][o] = pw_b + PW @ dw_b
      int t2 = idx - 174080;
      int i2 = t2 >> 7, o = t2 & 127;
      float a = pw_b[t2];
      const float* wrow = pw_w + (size_t)i2 * 16384 + o * 128;
      const float* db = dw_b + i2 * 128;
      for (int c2 = 0; c2 < 128; c2++) a += wrow[c2] * db[c2];
      beff[t2] = a;
    }
  }

  // ---- P1: res(bf16) = x + pos_enc (inline); per-block partials -> pstat0 ----
  {
    int bb = blockIdx.y, jx = blockIdx.x;
    int wv = tid >> 6, lane = tid & 63;
    float s1 = 0.f, s2 = 0.f;
    #pragma unroll 1
    for (int pass = 0; pass < 4; pass++) {
      int q = pass * 3584 + jx * 512 + tid;       // 12800 quads per b, 7 blocks
      if (q < 12800) {
        size_t idx4 = (size_t)bb * 12800 + q;
        int cl4 = q * 4;
        int c = cl4 / LL;
        int l = cl4 - c * LL;                     // l..l+3 same c (4 | 400)
        float fc2 = (float)c, freq, ph;
        if ((c & 1) == 0) { freq = powf(10000.f, -fc2 / (float)CC);        ph = 0.f; }
        else              { freq = -powf(10000.f, (1.f - fc2) / (float)CC); ph = 1.5707963267948966f; }
        const float4 xv = *reinterpret_cast<const float4*>(&x[idx4 * 4]);
        ushort4 h;
        h.x = (unsigned short)f2bf(xv.x + sinf((float)(l + 0) * freq + ph));
        h.y = (unsigned short)f2bf(xv.y + sinf((float)(l + 1) * freq + ph));
        h.z = (unsigned short)f2bf(xv.z + sinf((float)(l + 2) * freq + ph));
        h.w = (unsigned short)f2bf(xv.w + sinf((float)(l + 3) * freq + ph));
        *reinterpret_cast<ushort4*>(&r0[idx4 * 4]) = h;
        float v0 = bf2f(h.x), v1 = bf2f(h.y), v2 = bf2f(h.z), v3 = bf2f(h.w);
        s1 += v0 + v1 + v2 + v3;
        s2 += v0 * v0 + v1 * v1 + v2 * v2 + v3 * v3;
      }
    }
    #pragma unroll
    for (int off = 32; off > 0; off >>= 1) {
      s1 += __shfl_down(s1, off);
      s2 += __shfl_down(s2, off);
    }
    if (lane == 0) { red[wv * 2] = s1; red[wv * 2 + 1] = s2; }
    __syncthreads();
    if (tid == 0) {
      float a = 0.f, b2 = 0.f;
      #pragma unroll
      for (int w2 = 0; w2 < 8; w2++) { a += red[w2 * 2]; b2 += red[w2 * 2 + 1]; }
      pstat[(bb * 7 + jx) * 2 + 0] = a;
      pstat[(bb * 7 + jx) * 2 + 1] = b2;
    }
  }
  gbarrier(bar, 0);

  // ---- conv layers (LN+dwconv staged, MFMA, ReLU+resid, partial stats) ----
  gemm_body<2, 1, true, true, true>(XsF, red, wf + 0 * 16384, r0, beff + 0 * CC,
      r0, lng, lnb, dw_w + 0 * CC * KK, pstat + 0 * PSTRIDE, pstat + 1 * PSTRIDE, r1);
  gbarrier(bar, 1);
  gemm_body<2, 1, true, true, true>(XsF, red, wf + 1 * 16384, r1, beff + 1 * CC,
      r1, lng, lnb, dw_w + 1 * CC * KK, pstat + 1 * PSTRIDE, pstat + 2 * PSTRIDE, r0);
  gbarrier(bar, 2);
  gemm_body<2, 1, true, true, true>(XsF, red, wf + 2 * 16384, r0, beff + 2 * CC,
      r0, lng, lnb, dw_w + 2 * CC * KK, pstat + 2 * PSTRIDE, pstat + 3 * PSTRIDE, r1);
  gbarrier(bar, 3);
  gemm_body<2, 1, true, true, true>(XsF, red, wf + 3 * 16384, r1, beff + 3 * CC,
      r1, lng, lnb, dw_w + 3 * CC * KK, pstat + 3 * PSTRIDE, pstat + 4 * PSTRIDE, r0);
  gbarrier(bar, 4);

  // ---- QKV (one staging, 3 GEMMs) ----
  {
    int bb = blockIdx.y;
    int j0 = blockIdx.x * 64;
    int w = tid >> 6, lane = tid & 63;
    float s1 = 0.f, s2 = 0.f;
    #pragma unroll
    for (int k2 = 0; k2 < 7; k2++) {
      s1 += pstat[4 * PSTRIDE + (bb * 7 + k2) * 2 + 0];
      s2 += pstat[4 * PSTRIDE + (bb * 7 + k2) * 2 + 1];
    }
    float mu = s1 * INV_N;
    float rstd = rsqrtf(s2 * INV_N - mu * mu + EPSV);
    stage_x<0>(XsF, r0 + (size_t)bb * CL, j0, lng, lnb, nullptr, mu, rstd, tid);
    __syncthreads();
    int col = lane & 15, quad = lane >> 4;
    int obase = w * 16;
    #pragma unroll 1
    for (int m = 0; m < 3; m++) {
      const unsigned short* Wf = wf + (size_t)(4 + m) * 16384;
      const float* bias = (m == 0) ? bq : (m == 1) ? bk : bvp;
      bf16x8 af[4];
      #pragma unroll
      for (int kt2 = 0; kt2 < 4; kt2++)
        af[kt2] = *reinterpret_cast<const bf16x8*>(&Wf[(w * 4 + kt2) * 512 + lane * 8]);
      f32x4 acc[4];
      #pragma unroll
      for (int lf = 0; lf < 4; lf++) acc[lf] = (f32x4){0.f, 0.f, 0.f, 0.f};
      #pragma unroll
      for (int kt2 = 0; kt2 < 4; kt2++) {
        #pragma unroll
        for (int lf = 0; lf < 4; lf++) {
          bf16x8 bx = *reinterpret_cast<const bf16x8*>(&XsF[(lf * 4 + kt2) * 512 + lane * 8]);
          acc[lf] = __builtin_amdgcn_mfma_f32_16x16x32_bf16(af[kt2], bx, acc[lf], 0, 0, 0);
        }
      }
      float bv4[4];
      #pragma unroll
      for (int r = 0; r < 4; r++) bv4[r] = bias[obase + quad * 4 + r];
      if (m < 2) {
        unsigned short* dst = (m == 0) ? qt : kt;
        #pragma unroll
        for (int lf = 0; lf < 4; lf++) {
          if (j0 + lf * 16 < LL) {
            int l = j0 + lf * 16 + col;
            short4 hv4 = {f2bf(acc[lf][0] + bv4[0]), f2bf(acc[lf][1] + bv4[1]),
                          f2bf(acc[lf][2] + bv4[2]), f2bf(acc[lf][3] + bv4[3])};
            *reinterpret_cast<short4*>(
                &dst[(((size_t)bb * 8 + w) * LL + l) * 16 + quad * 4]) = hv4;
          }
        }
      } else {
        #pragma unroll
        for (int lf = 0; lf < 4; lf++) {
          if (j0 + lf * 16 < LL) {
            int l = j0 + lf * 16 + col;
            #pragma unroll
            for (int r = 0; r < 4; r++) {
              float v = acc[lf][r] + bv4[r];
              vbf[(size_t)bb * CL + (size_t)(obase + quad * 4 + r) * LL + l] =
                  (unsigned short)f2bf(v);
            }
          }
        }
      }
    }
  }
}

// ---------------------------------------------------------------------------
// WO + FC fused (persistent, barrier slot 5): wo -> pstat5, barrier, fc -> out
// ---------------------------------------------------------------------------
__global__ __launch_bounds__(512, 4) void wo_fc_fused(
    const unsigned short* __restrict__ wf, const float* __restrict__ bo,
    const float* __restrict__ fcb, const unsigned short* __restrict__ tb,
    const unsigned short* __restrict__ r0, unsigned short* __restrict__ r1,
    const float* __restrict__ lng, const float* __restrict__ lnb,
    float* __restrict__ pstat, float* __restrict__ out, int* __restrict__ bar)
{
  __shared__ short XsF[16 * 512];
  __shared__ float red[16];
  // WO projection + residual -> r1 (bf16), pstat5
  gemm_body<1, 1, false, true, true>(XsF, red, wf + 7 * 16384, tb, bo, r0,
      nullptr, nullptr, nullptr, nullptr, pstat + 5 * PSTRIDE, r1);
  gbarrier(bar, 5);
  // FC (LN on load) + ReLU + residual -> out (fp32)
  gemm_body<0, 0, true, true, false>(XsF, red, wf + 8 * 16384, r1, fcb, r1,
      lng, lnb, nullptr, pstat + 5 * PSTRIDE, nullptr, out);
}

// ---------------------------------------------------------------------------
// attention: 4 waves/block = 2 l-tiles x 2 m-halves (static-max softmax
// partials combine additively). 16-row f-level double-buffered P per wave.
// ---------------------------------------------------------------------------
__global__ __launch_bounds__(256, 4) void attn_kernel(
    const unsigned short* __restrict__ qt, const unsigned short* __restrict__ kt,
    const unsigned short* __restrict__ vb, const float* __restrict__ maddb,
    unsigned short* __restrict__ ao)
{
  __shared__ short Pl[4][2][640];           // 10240 B: per-wave f-level dbuf
  __shared__ float Mg[2][64][20];           // 10240 B: merge of[16]+psum[4]
  int bh = blockIdx.x;
  int b = bh >> 3, h = bh & 7;
  int w = threadIdx.x >> 6, lane = threadIdx.x & 63;
  int pair = w >> 1, half = w & 1;
  int tile = blockIdx.y * 2 + pair;
  bool live = tile < 7;
  int tile_c = live ? tile : 6;
  int col = lane & 15, quad = lane >> 4;
  int l0 = tile_c * 64;
  size_t trow = ((size_t)b * 8 + h) * LL;
  size_t base = ((size_t)b * CC + h * DK) * LL;
  const unsigned short* qp = qt + trow * 16;
  const unsigned short* kp = kt + trow * 16;
  const unsigned short* vp = vb + base;
  const float* mb = maddb + (size_t)b * 416;

  bf16x8 qf[4];
  #pragma unroll
  for (int f = 0; f < 4; f++) {
    bf16x8 v = {};
    if (quad < 2) {
      int l = l0 + f * 16 + col; int lc = l < LL ? l : LL - 1;
      v = *reinterpret_cast<const bf16x8*>(&qp[lc * 16 + quad * 8]);
    }
    qf[f] = v;
  }
  f32x4 of[4];
  float psum[4];
  #pragma unroll
  for (int f = 0; f < 4; f++) {
    of[f] = (f32x4){0.f, 0.f, 0.f, 0.f};
    psum[f] = 0.f;
  }
  const float scale2 = 0.08838834764831845f * 1.4426950408889634f;  // /sqrt(128)*log2e

  int mstart = half ? 224 : 0;
  int mend   = half ? 416 : 224;            // 6 / 7 steps of 32
  for (int m0 = mstart; m0 < mend; m0 += 32) {
    bf16x8 kf0 = {}, kf1 = {};
    if (quad < 2) {
      int mc0 = m0 + col < LL ? m0 + col : LL - 1;
      int mc1 = m0 + 16 + col < LL ? m0 + 16 + col : LL - 1;
      kf0 = *reinterpret_cast<const bf16x8*>(&kp[mc0 * 16 + quad * 8]);
      kf1 = *reinterpret_cast<const bf16x8*>(&kp[mc1 * 16 + quad * 8]);
    }
    bf16x8 vf;
    {
      int ms = m0 + quad * 8; if (ms > LL - 8) ms = LL - 8;
      vf = *reinterpret_cast<const bf16x8*>(&vp[col * LL + ms]);
    }
    const float4 a4 = *reinterpret_cast<const float4*>(&mb[m0 + quad * 4]);
    const float4 b4 = *reinterpret_cast<const float4*>(&mb[m0 + 16 + quad * 4]);
    float madd[8] = {a4.x, a4.y, a4.z, a4.w, b4.x, b4.y, b4.z, b4.w};
    #pragma unroll
    for (int f = 0; f < 4; f++) {
      f32x4 z = {0.f, 0.f, 0.f, 0.f};
      f32x4 s0 = __builtin_amdgcn_mfma_f32_16x16x32_bf16(kf0, qf[f], z, 0, 0, 0);
      f32x4 s1 = __builtin_amdgcn_mfma_f32_16x16x32_bf16(kf1, qf[f], z, 0, 0, 0);
      float p[8];
      #pragma unroll
      for (int r = 0; r < 4; r++) {
        p[r]     = EXP2F(s0[r] * scale2 + madd[r]);
        p[4 + r] = EXP2F(s1[r] * scale2 + madd[4 + r]);
      }
      float ps = 0.f;
      #pragma unroll
      for (int i = 0; i < 8; i++) ps += p[i];
      psum[f] += ps;
      short* row = &Pl[w][f & 1][col * 40];
      short4 h0 = __builtin_bit_cast(short4, make_uint2(pkbf(p[1], p[0]), pkbf(p[3], p[2])));
      short4 h1 = __builtin_bit_cast(short4, make_uint2(pkbf(p[5], p[4]), pkbf(p[7], p[6])));
      *reinterpret_cast<short4*>(&row[quad * 4])      = h0;
      *reinterpret_cast<short4*>(&row[16 + quad * 4]) = h1;
      bf16x8 pf = *reinterpret_cast<const bf16x8*>(&Pl[w][f & 1][col * 40 + quad * 8]);
      of[f] = __builtin_amdgcn_mfma_f32_16x16x32_bf16(vf, pf, of[f], 0, 0, 0);
    }
  }
  // merge halves: half-1 waves publish partials, half-0 waves combine
  if (half == 1) {
    float* mg = &Mg[pair][lane][0];
    #pragma unroll
    for (int f = 0; f < 4; f++) {
      #pragma unroll
      for (int r = 0; r < 4; r++) mg[f * 4 + r] = of[f][r];
      mg[16 + f] = psum[f];
    }
  }
  __syncthreads();
  if (half == 0 && live) {
    const float* mg = &Mg[pair][lane][0];
    #pragma unroll
    for (int f = 0; f < 4; f++) {
      #pragma unroll
      for (int r = 0; r < 4; r++) of[f][r] += mg[f * 4 + r];
      psum[f] += mg[16 + f];
    }
    #pragma unroll
    for (int f = 0; f < 4; f++) {
      float s = psum[f];
      s += __shfl_xor(s, 16);
      s += __shfl_xor(s, 32);
      float inv = 1.f / s;
      int lf = l0 + f * 16;
      if (lf < LL) {
        #pragma unroll
        for (int r = 0; r < 4; r++)
          ao[base + (size_t)(quad * 4 + r) * LL + lf + col] =
              (unsigned short)f2bf(of[f][r] * inv);
      }
    }
  }
}

// ---------------------------------------------------------------------------
extern "C" void kernel_launch(void* const* d_in, const int* in_sizes, int n_in,
                              void* d_out, int out_size, void* d_ws, size_t ws_size,
                              hipStream_t stream) {
  const float* x    = (const float*)d_in[0];
  const float* mask = (const float*)d_in[1];
  const float* dw_w = (const float*)d_in[2];
  const float* dw_b = (const float*)d_in[3];
  const float* pw_w = (const float*)d_in[4];
  const float* pw_b = (const float*)d_in[5];
  const float* wq   = (const float*)d_in[6];
  const float* bq   = (const float*)d_in[7];
  const float* wk   = (const float*)d_in[8];
  const float* bk   = (const float*)d_in[9];
  const float* wvp  = (const float*)d_in[10];
  const float* bv   = (const float*)d_in[11];
  const float* wo   = (const float*)d_in[12];
  const float* bo   = (const float*)d_in[13];
  const float* fcw  = (const float*)d_in[14];
  const float* fcb  = (const float*)d_in[15];
  const float* lng  = (const float*)d_in[16];
  const float* lnb  = (const float*)d_in[17];
  float* out = (float*)d_out;
  float* ws  = (float*)d_ws;

  float* pstat = ws + 1024;                             // 6*896 f partials
  float* beff  = ws + 1024 + 51200;                     // 512 f
  float* maddb = beff + 512;                            // 64*416 f
  unsigned short* wf = (unsigned short*)(maddb + 64 * 416); // 9*16384 bf16
  unsigned short* r0 = wf + 9 * 16384;                  // NBCL bf16 each:
  unsigned short* r1 = r0 + NBCL;
  unsigned short* qt = r1 + NBCL;
  unsigned short* kt = qt + NBCL;
  unsigned short* vbf = kt + NBCL;
  unsigned short* tb = vbf + NBCL;
  int* bar = (int*)(tb + NBCL);                         // 8 slots x 32 ints

  hipMemsetAsync(bar, 0, 8 * 32 * sizeof(int), stream); // zero barrier slots

  fused_main<<<dim3(7, BN), 512, 0, stream>>>(
      pw_w, wq, wk, wvp, wo, fcw, pw_b, dw_b, mask, x, lng, lnb, dw_w,
      bq, bk, bv, wf, pstat, beff, maddb, r0, r1, qt, kt, vbf, bar);
  attn_kernel<<<dim3(512, 4), 256, 0, stream>>>(qt, kt, vbf, maddb, tb);
  wo_fc_fused<<<dim3(7, BN), 512, 0, stream>>>(
      wf, bo, fcb, tb, r0, r1, lng, lnb, pstat, out, bar);
}

// Round 8
// 435.586 us; speedup vs baseline: 4.0687x; 1.2973x over previous
//
#include <hip/hip_runtime.h>
#include <math.h>

constexpr int BN = 64;
constexpr int CC = 128;
constexpr int LL = 400;
constexpr int DK = 16;
constexpr int KK = 7;
constexpr int CL = CC * LL;              // 51200
constexpr int NBCL = BN * CL;            // 3276800
constexpr float EPSV = 1e-5f;
constexpr float INV_N = 1.0f / (float)CL;
constexpr float BIGL = 1.4427e30f;
constexpr int PSTRIDE = BN * 7 * 2;      // 896 floats per stats layer

typedef __attribute__((ext_vector_type(8))) short bf16x8;
typedef __attribute__((ext_vector_type(4))) float f32x4;

#if defined(__has_builtin)
#if __has_builtin(__builtin_amdgcn_exp2f)
#define EXP2F(x) __builtin_amdgcn_exp2f(x)
#endif
#endif
#ifndef EXP2F
#define EXP2F(x) exp2f(x)
#endif

__device__ __forceinline__ short f2bf(float f) {        // RNE
  unsigned u = __builtin_bit_cast(unsigned, f);
  u = (u + 0x7fffu + ((u >> 16) & 1u)) >> 16;
  return (short)u;
}
__device__ __forceinline__ float bf2f(unsigned short u) {
  return __builtin_bit_cast(float, (unsigned)u << 16);
}
__device__ __forceinline__ unsigned pkbf(float hi, float lo) {  // truncate-pack
  return __builtin_amdgcn_perm(__builtin_bit_cast(unsigned, hi),
                               __builtin_bit_cast(unsigned, lo), 0x07060302u);
}

// ---------------------------------------------------------------------------
// Per-batch barrier (7 blocks of one bb). Round-7 global barrier cost ~60us:
// 448 pollers + RMWs on ONE line serialize at the coherence point, and the
// global barrier couples all blocks to the slowest straggler. Per-batch:
// 7 RMW + 7 pollers per line, 64 independent lines. Every phase's dependency
// closure is per-batch (LN stats per b; conv halo is jx+-1 of same b).
// Fences: thread0-only wbl2 (release) / inv (acquire) for cross-XCD visibility.
// ---------------------------------------------------------------------------
__device__ __forceinline__ void bbarrier(int* bar, int use, int bb) {
  __syncthreads();                 // drains block's vmcnt (stores in local L2)
  if (threadIdx.x == 0) {
    __threadfence();               // release: writeback local L2
    int* p = bar + (use * 64 + bb) * 32;   // own cacheline per (use,bb)
    __hip_atomic_fetch_add(p, 1, __ATOMIC_RELAXED, __HIP_MEMORY_SCOPE_AGENT);
    while (__hip_atomic_load(p, __ATOMIC_RELAXED, __HIP_MEMORY_SCOPE_AGENT) < 7)
      __builtin_amdgcn_s_sleep(1);
    __threadfence();               // acquire: invalidate stale L1/L2
  }
  __syncthreads();
}

// ---------------------------------------------------------------------------
// X staging (bf16 inputs) into fragment-ordered LDS tile, 8-wide groups.
// XMODE 0: + LN; XMODE 1: direct copy; XMODE 2: + LN + conv7 (+db fold)
// ---------------------------------------------------------------------------
template<int XMODE>
__device__ __forceinline__ void stage_x(
    short* __restrict__ XsF, const unsigned short* __restrict__ Xb,
    int j0, const float* __restrict__ lng, const float* __restrict__ lnb,
    const float* __restrict__ dww, const float* __restrict__ dwb,
    float mu, float rstd, int tid)
{
  for (int idx = tid; idx < 1024; idx += 512) {
    int c = idx >> 3;
    int l8 = (idx & 7) * 8;
    int col0 = j0 + l8;
    short hv[8];
    if (XMODE == 2) {
      const unsigned short* rp = Xb + c * LL;
      const float* gp = lng + c * LL;
      const float* bp = lnb + c * LL;
      float xn[16];
      #pragma unroll
      for (int g4 = 0; g4 < 4; g4++) {
        int p0 = col0 - 4 + g4 * 4;
        int pc = p0 < 0 ? 0 : (p0 > LL - 4 ? LL - 4 : p0);
        const ushort4 rv = *reinterpret_cast<const ushort4*>(&rp[pc]);
        const float4 gv = *reinterpret_cast<const float4*>(&gp[pc]);
        const float4 bv4 = *reinterpret_cast<const float4*>(&bp[pc]);
        float rr[4] = {bf2f(rv.x), bf2f(rv.y), bf2f(rv.z), bf2f(rv.w)};
        float gg[4] = {gv.x, gv.y, gv.z, gv.w};
        float bbv[4] = {bv4.x, bv4.y, bv4.z, bv4.w};
        #pragma unroll
        for (int e = 0; e < 4; e++) {
          int p = p0 + e;
          float v = (rr[e] - mu) * rstd * gg[e] + bbv[e];
          xn[g4 * 4 + e] = (p >= 0 && p < LL) ? v : 0.f;
        }
      }
      float w7[KK];
      #pragma unroll
      for (int j = 0; j < KK; j++) w7[j] = dww[c * KK + j];
      float dbc = dwb[c];                  // db folded into staged operand
      #pragma unroll
      for (int e = 0; e < 8; e++) {
        float a = 0.f;
        #pragma unroll
        for (int jj = 0; jj < KK; jj++) a += w7[jj] * xn[e + jj + 1];
        hv[e] = f2bf(a + dbc);
      }
    } else {
      bool valid = col0 < LL;               // LL % 8 == 0: all-or-nothing
      int col0c = valid ? col0 : 0;
      const unsigned short* xp = Xb + c * LL + col0c;
      const ushort4 u0 = *reinterpret_cast<const ushort4*>(&xp[0]);
      const ushort4 u1 = *reinterpret_cast<const ushort4*>(&xp[4]);
      unsigned short uu[8] = {u0.x, u0.y, u0.z, u0.w, u1.x, u1.y, u1.z, u1.w};
      if (XMODE == 1) {
        #pragma unroll
        for (int e = 0; e < 8; e++) hv[e] = valid ? (short)uu[e] : (short)0;
      } else {
        const float* gp = lng + c * LL + col0c;
        const float* bp = lnb + c * LL + col0c;
        const float4 g0 = *reinterpret_cast<const float4*>(&gp[0]);
        const float4 g1 = *reinterpret_cast<const float4*>(&gp[4]);
        const float4 b0 = *reinterpret_cast<const float4*>(&bp[0]);
        const float4 b1 = *reinterpret_cast<const float4*>(&bp[4]);
        float gg[8] = {g0.x, g0.y, g0.z, g0.w, g1.x, g1.y, g1.z, g1.w};
        float bbv[8] = {b0.x, b0.y, b0.z, b0.w, b1.x, b1.y, b1.z, b1.w};
        #pragma unroll
        for (int e = 0; e < 8; e++) {
          float v = (bf2f(uu[e]) - mu) * rstd * gg[e] + bbv[e];
          hv[e] = valid ? f2bf(v) : (short)0;
        }
      }
    }
    int t = (l8 >> 4) * 4 + (c >> 5);
    int quad = (c >> 3) & 3;
    int j = c & 7;
    int base = t * 512 + quad * 128 + j;
    int colb = l8 & 15;
    #pragma unroll
    for (int e = 0; e < 8; e++) XsF[base + (colb + e) * 8] = hv[e];
  }
}

// ---------------------------------------------------------------------------
// GEMM phase. W loaded DIRECTLY from fp32 row-major [o][c] (no prep pass):
// frag (w,lane,kt) <-> o = w*16+(lane&15), c = kt*32+(lane>>4)*8 + j (j=0..7
// consecutive) -- two float4 loads + 8 RNE converts, bit-identical to the
// old wf path. LN stats via per-block partials (sum 7 per b, no atomics).
// OMODE 0: fp32 linear; 1: bf16 linear; 2: bf16 transposed (b,h,l,d)
// ---------------------------------------------------------------------------
template<int XMODE, int OMODE, bool RELU, bool ADDRES, bool STATS>
__device__ __forceinline__ void gemm_body(
    short* __restrict__ XsF, float* __restrict__ red,
    const float* __restrict__ Wsrc, const unsigned short* __restrict__ Xv,
    const float* __restrict__ bias, const unsigned short* __restrict__ resid,
    const float* __restrict__ lng, const float* __restrict__ lnb,
    const float* __restrict__ dww, const float* __restrict__ dwb,
    const float* __restrict__ statsIn, float* __restrict__ statsOut,
    void* __restrict__ Yv)
{
  int tid = threadIdx.x;
  int bb = blockIdx.y;
  int j0 = blockIdx.x * 64;
  int w = tid >> 6, lane = tid & 63;
  int o = w * 16 + (lane & 15);
  int cb = (lane >> 4) * 8;
  bf16x8 af[4];
  #pragma unroll
  for (int kt = 0; kt < 4; kt++) {
    const float* wp = Wsrc + o * 128 + kt * 32 + cb;
    const float4 a0 = *reinterpret_cast<const float4*>(wp);
    const float4 a1 = *reinterpret_cast<const float4*>(wp + 4);
    bf16x8 v;
    v[0] = f2bf(a0.x); v[1] = f2bf(a0.y); v[2] = f2bf(a0.z); v[3] = f2bf(a0.w);
    v[4] = f2bf(a1.x); v[5] = f2bf(a1.y); v[6] = f2bf(a1.z); v[7] = f2bf(a1.w);
    af[kt] = v;
  }
  float mu = 0.f, rstd = 0.f;
  if (XMODE != 1) {
    float s1 = 0.f, s2 = 0.f;
    #pragma unroll
    for (int k2 = 0; k2 < 7; k2++) {
      s1 += statsIn[(bb * 7 + k2) * 2 + 0];
      s2 += statsIn[(bb * 7 + k2) * 2 + 1];
    }
    mu = s1 * INV_N;
    rstd = rsqrtf(s2 * INV_N - mu * mu + EPSV);
  }
  stage_x<XMODE>(XsF, Xv + (size_t)bb * CL, j0, lng, lnb, dww, dwb, mu, rstd, tid);
  __syncthreads();
  int col = lane & 15, quad = lane >> 4;
  f32x4 acc[4];
  #pragma unroll
  for (int lf = 0; lf < 4; lf++) acc[lf] = (f32x4){0.f, 0.f, 0.f, 0.f};
  #pragma unroll
  for (int kt = 0; kt < 4; kt++) {
    #pragma unroll
    for (int lf = 0; lf < 4; lf++) {
      bf16x8 bx = *reinterpret_cast<const bf16x8*>(&XsF[(lf * 4 + kt) * 512 + lane * 8]);
      acc[lf] = __builtin_amdgcn_mfma_f32_16x16x32_bf16(af[kt], bx, acc[lf], 0, 0, 0);
    }
  }
  int obase = w * 16;
  float bv[4];
  #pragma unroll
  for (int r = 0; r < 4; r++) bv[r] = bias[obase + quad * 4 + r];
  float lsum = 0.f, lsq = 0.f;
  #pragma unroll
  for (int lf = 0; lf < 4; lf++) {
    if (j0 + lf * 16 < LL) {
      int l = j0 + lf * 16 + col;
      if (OMODE == 2) {
        short4 hv4 = {f2bf(acc[lf][0] + bv[0]), f2bf(acc[lf][1] + bv[1]),
                      f2bf(acc[lf][2] + bv[2]), f2bf(acc[lf][3] + bv[3])};
        *reinterpret_cast<short4*>(
            &((unsigned short*)Yv)[(((size_t)bb * 8 + w) * LL + l) * 16 + quad * 4]) = hv4;
      } else {
        #pragma unroll
        for (int r = 0; r < 4; r++) {
          float v = acc[lf][r] + bv[r];
          if (RELU) v = fmaxf(v, 0.f);
          size_t oidx = (size_t)bb * CL + (size_t)(obase + quad * 4 + r) * LL + l;
          if (ADDRES) v += bf2f(resid[oidx]);
          if (OMODE == 1) {
            unsigned short hb = (unsigned short)f2bf(v);
            ((unsigned short*)Yv)[oidx] = hb;
            if (STATS) { float vf = bf2f(hb); lsum += vf; lsq += vf * vf; }
          } else {
            ((float*)Yv)[oidx] = v;
            if (STATS) { lsum += v; lsq += v * v; }
          }
        }
      }
    }
  }
  if (STATS) {
    #pragma unroll
    for (int off = 32; off > 0; off >>= 1) {
      lsum += __shfl_down(lsum, off);
      lsq  += __shfl_down(lsq, off);
    }
    if (lane == 0) { red[w * 2] = lsum; red[w * 2 + 1] = lsq; }
    __syncthreads();
    if (tid == 0) {
      float a = 0.f, b2 = 0.f;
      #pragma unroll
      for (int w2 = 0; w2 < 8; w2++) { a += red[w2 * 2]; b2 += red[w2 * 2 + 1]; }
      statsOut[(bb * 7 + blockIdx.x) * 2 + 0] = a;     // partial, no atomic
      statsOut[(bb * 7 + blockIdx.x) * 2 + 1] = b2;
    }
  }
}

// ---------------------------------------------------------------------------
// FUSED MAIN (grid (7,64) x 512, PER-BATCH barriers):
//   P0 maddb (no consumer inside this kernel)  ||  P1 addpos+pos-enc -> pstat0
//   b-bar -> conv1..conv4 (b-bars between) -> qkv.
// Weights converted in-register from fp32 (no global prep dependency).
// ---------------------------------------------------------------------------
__global__ __launch_bounds__(512, 4) void fused_main(
    const float* __restrict__ pw_w, const float* __restrict__ wq,
    const float* __restrict__ wk, const float* __restrict__ wvp,
    const float* __restrict__ pw_b, const float* __restrict__ dw_b,
    const float* __restrict__ mask, const float* __restrict__ x,
    const float* __restrict__ lng, const float* __restrict__ lnb,
    const float* __restrict__ dw_w,
    const float* __restrict__ bq, const float* __restrict__ bk,
    const float* __restrict__ bvp,
    float* __restrict__ pstat, float* __restrict__ maddb,
    unsigned short* __restrict__ r0, unsigned short* __restrict__ r1,
    unsigned short* __restrict__ qt, unsigned short* __restrict__ kt,
    unsigned short* __restrict__ vbf, int* __restrict__ bar)
{
  __shared__ short XsF[16 * 512];
  __shared__ float red[16];
  int tid = threadIdx.x;
  int blockFlat = blockIdx.y * 7 + blockIdx.x;      // grid (7,64)
  int gtid = blockFlat * 512 + tid;
  int bb = blockIdx.y;

  // ---- P0: additive attention mask (consumed only by attn dispatch) ----
  {
    int idx = gtid;
    if (idx < 26624) {                   // 64 x 416
      int b = idx / 416, m = idx - b * 416;
      maddb[idx] = (m < LL) ? (mask[b * LL + m] - 1.f) * BIGL : -BIGL;
    }
  }

  // ---- P1: res(bf16) = x + pos_enc (inline); per-block partials -> pstat0 ----
  {
    int jx = blockIdx.x;
    int wv = tid >> 6, lane = tid & 63;
    float s1 = 0.f, s2 = 0.f;
    #pragma unroll 1
    for (int pass = 0; pass < 4; pass++) {
      int q = pass * 3584 + jx * 512 + tid;       // 12800 quads per b, 7 blocks
      if (q < 12800) {
        size_t idx4 = (size_t)bb * 12800 + q;
        int cl4 = q * 4;
        int c = cl4 / LL;
        int l = cl4 - c * LL;                     // l..l+3 same c (4 | 400)
        float fc2 = (float)c, freq, ph;
        if ((c & 1) == 0) { freq = powf(10000.f, -fc2 / (float)CC);        ph = 0.f; }
        else              { freq = -powf(10000.f, (1.f - fc2) / (float)CC); ph = 1.5707963267948966f; }
        const float4 xv = *reinterpret_cast<const float4*>(&x[idx4 * 4]);
        ushort4 h;
        h.x = (unsigned short)f2bf(xv.x + sinf((float)(l + 0) * freq + ph));
        h.y = (unsigned short)f2bf(xv.y + sinf((float)(l + 1) * freq + ph));
        h.z = (unsigned short)f2bf(xv.z + sinf((float)(l + 2) * freq + ph));
        h.w = (unsigned short)f2bf(xv.w + sinf((float)(l + 3) * freq + ph));
        *reinterpret_cast<ushort4*>(&r0[idx4 * 4]) = h;
        float v0 = bf2f(h.x), v1 = bf2f(h.y), v2 = bf2f(h.z), v3 = bf2f(h.w);
        s1 += v0 + v1 + v2 + v3;
        s2 += v0 * v0 + v1 * v1 + v2 * v2 + v3 * v3;
      }
    }
    #pragma unroll
    for (int off = 32; off > 0; off >>= 1) {
      s1 += __shfl_down(s1, off);
      s2 += __shfl_down(s2, off);
    }
    if (lane == 0) { red[wv * 2] = s1; red[wv * 2 + 1] = s2; }
    __syncthreads();
    if (tid == 0) {
      float a = 0.f, b2 = 0.f;
      #pragma unroll
      for (int w2 = 0; w2 < 8; w2++) { a += red[w2 * 2]; b2 += red[w2 * 2 + 1]; }
      pstat[(bb * 7 + jx) * 2 + 0] = a;
      pstat[(bb * 7 + jx) * 2 + 1] = b2;
    }
  }
  bbarrier(bar, 0, bb);

  // ---- conv layers (LN+dwconv+db staged, MFMA, ReLU+resid, partial stats) ----
  gemm_body<2, 1, true, true, true>(XsF, red, pw_w + 0 * 16384, r0, pw_b + 0 * CC,
      r0, lng, lnb, dw_w + 0 * CC * KK, dw_b + 0 * CC,
      pstat + 0 * PSTRIDE, pstat + 1 * PSTRIDE, r1);
  bbarrier(bar, 1, bb);
  gemm_body<2, 1, true, true, true>(XsF, red, pw_w + 1 * 16384, r1, pw_b + 1 * CC,
      r1, lng, lnb, dw_w + 1 * CC * KK, dw_b + 1 * CC,
      pstat + 1 * PSTRIDE, pstat + 2 * PSTRIDE, r0);
  bbarrier(bar, 2, bb);
  gemm_body<2, 1, true, true, true>(XsF, red, pw_w + 2 * 16384, r0, pw_b + 2 * CC,
      r0, lng, lnb, dw_w + 2 * CC * KK, dw_b + 2 * CC,
      pstat + 2 * PSTRIDE, pstat + 3 * PSTRIDE, r1);
  bbarrier(bar, 3, bb);
  gemm_body<2, 1, true, true, true>(XsF, red, pw_w + 3 * 16384, r1, pw_b + 3 * CC,
      r1, lng, lnb, dw_w + 3 * CC * KK, dw_b + 3 * CC,
      pstat + 3 * PSTRIDE, pstat + 4 * PSTRIDE, r0);
  bbarrier(bar, 4, bb);

  // ---- QKV (one staging, 3 GEMMs, W direct from fp32) ----
  {
    int j0 = blockIdx.x * 64;
    int w = tid >> 6, lane = tid & 63;
    float s1 = 0.f, s2 = 0.f;
    #pragma unroll
    for (int k2 = 0; k2 < 7; k2++) {
      s1 += pstat[4 * PSTRIDE + (bb * 7 + k2) * 2 + 0];
      s2 += pstat[4 * PSTRIDE + (bb * 7 + k2) * 2 + 1];
    }
    float mu = s1 * INV_N;
    float rstd = rsqrtf(s2 * INV_N - mu * mu + EPSV);
    stage_x<0>(XsF, r0 + (size_t)bb * CL, j0, lng, lnb, nullptr, nullptr,
               mu, rstd, tid);
    __syncthreads();
    int col = lane & 15, quad = lane >> 4;
    int obase = w * 16;
    int o = w * 16 + (lane & 15);
    int cb = (lane >> 4) * 8;
    #pragma unroll 1
    for (int m = 0; m < 3; m++) {
      const float* Wsrc = (m == 0) ? wq : (m == 1) ? wk : wvp;
      const float* bias = (m == 0) ? bq : (m == 1) ? bk : bvp;
      bf16x8 af[4];
      #pragma unroll
      for (int kt2 = 0; kt2 < 4; kt2++) {
        const float* wp = Wsrc + o * 128 + kt2 * 32 + cb;
        const float4 a0 = *reinterpret_cast<const float4*>(wp);
        const float4 a1 = *reinterpret_cast<const float4*>(wp + 4);
        bf16x8 v;
        v[0] = f2bf(a0.x); v[1] = f2bf(a0.y); v[2] = f2bf(a0.z); v[3] = f2bf(a0.w);
        v[4] = f2bf(a1.x); v[5] = f2bf(a1.y); v[6] = f2bf(a1.z); v[7] = f2bf(a1.w);
        af[kt2] = v;
      }
      f32x4 acc[4];
      #pragma unroll
      for (int lf = 0; lf < 4; lf++) acc[lf] = (f32x4){0.f, 0.f, 0.f, 0.f};
      #pragma unroll
      for (int kt2 = 0; kt2 < 4; kt2++) {
        #pragma unroll
        for (int lf = 0; lf < 4; lf++) {
          bf16x8 bx = *reinterpret_cast<const bf16x8*>(&XsF[(lf * 4 + kt2) * 512 + lane * 8]);
          acc[lf] = __builtin_amdgcn_mfma_f32_16x16x32_bf16(af[kt2], bx, acc[lf], 0, 0, 0);
        }
      }
      float bv4[4];
      #pragma unroll
      for (int r = 0; r < 4; r++) bv4[r] = bias[obase + quad * 4 + r];
      if (m < 2) {
        unsigned short* dst = (m == 0) ? qt : kt;
        #pragma unroll
        for (int lf = 0; lf < 4; lf++) {
          if (j0 + lf * 16 < LL) {
            int l = j0 + lf * 16 + col;
            short4 hv4 = {f2bf(acc[lf][0] + bv4[0]), f2bf(acc[lf][1] + bv4[1]),
                          f2bf(acc[lf][2] + bv4[2]), f2bf(acc[lf][3] + bv4[3])};
            *reinterpret_cast<short4*>(
                &dst[(((size_t)bb * 8 + w) * LL + l) * 16 + quad * 4]) = hv4;
          }
        }
      } else {
        #pragma unroll
        for (int lf = 0; lf < 4; lf++) {
          if (j0 + lf * 16 < LL) {
            int l = j0 + lf * 16 + col;
            #pragma unroll
            for (int r = 0; r < 4; r++) {
              float v = acc[lf][r] + bv4[r];
              vbf[(size_t)bb * CL + (size_t)(obase + quad * 4 + r) * LL + l] =
                  (unsigned short)f2bf(v);
            }
          }
        }
      }
    }
  }
}

// ---------------------------------------------------------------------------
// WO + FC fused (per-batch barrier slot 5): wo -> pstat5, b-bar, fc -> out
// ---------------------------------------------------------------------------
__global__ __launch_bounds__(512, 4) void wo_fc_fused(
    const float* __restrict__ wo, const float* __restrict__ fcw,
    const float* __restrict__ bo, const float* __restrict__ fcb,
    const unsigned short* __restrict__ tb,
    const unsigned short* __restrict__ r0, unsigned short* __restrict__ r1,
    const float* __restrict__ lng, const float* __restrict__ lnb,
    float* __restrict__ pstat, float* __restrict__ out, int* __restrict__ bar)
{
  __shared__ short XsF[16 * 512];
  __shared__ float red[16];
  // WO projection + residual -> r1 (bf16), pstat5
  gemm_body<1, 1, false, true, true>(XsF, red, wo, tb, bo, r0,
      nullptr, nullptr, nullptr, nullptr, nullptr, pstat + 5 * PSTRIDE, r1);
  bbarrier(bar, 5, blockIdx.y);
  // FC (LN on load) + ReLU + residual -> out (fp32)
  gemm_body<0, 0, true, true, false>(XsF, red, fcw, r1, fcb, r1,
      lng, lnb, nullptr, nullptr, pstat + 5 * PSTRIDE, nullptr, out);
}

// ---------------------------------------------------------------------------
// attention: 4 waves/block = 2 l-tiles x 2 m-halves (static-max softmax
// partials combine additively). 16-row f-level double-buffered P per wave.
// ---------------------------------------------------------------------------
__global__ __launch_bounds__(256, 4) void attn_kernel(
    const unsigned short* __restrict__ qt, const unsigned short* __restrict__ kt,
    const unsigned short* __restrict__ vb, const float* __restrict__ maddb,
    unsigned short* __restrict__ ao)
{
  __shared__ short Pl[4][2][640];           // 10240 B: per-wave f-level dbuf
  __shared__ float Mg[2][64][20];           // 10240 B: merge of[16]+psum[4]
  int bh = blockIdx.x;
  int b = bh >> 3, h = bh & 7;
  int w = threadIdx.x >> 6, lane = threadIdx.x & 63;
  int pair = w >> 1, half = w & 1;
  int tile = blockIdx.y * 2 + pair;
  bool live = tile < 7;
  int tile_c = live ? tile : 6;
  int col = lane & 15, quad = lane >> 4;
  int l0 = tile_c * 64;
  size_t trow = ((size_t)b * 8 + h) * LL;
  size_t base = ((size_t)b * CC + h * DK) * LL;
  const unsigned short* qp = qt + trow * 16;
  const unsigned short* kp = kt + trow * 16;
  const unsigned short* vp = vb + base;
  const float* mb = maddb + (size_t)b * 416;

  bf16x8 qf[4];
  #pragma unroll
  for (int f = 0; f < 4; f++) {
    bf16x8 v = {};
    if (quad < 2) {
      int l = l0 + f * 16 + col; int lc = l < LL ? l : LL - 1;
      v = *reinterpret_cast<const bf16x8*>(&qp[lc * 16 + quad * 8]);
    }
    qf[f] = v;
  }
  f32x4 of[4];
  float psum[4];
  #pragma unroll
  for (int f = 0; f < 4; f++) {
    of[f] = (f32x4){0.f, 0.f, 0.f, 0.f};
    psum[f] = 0.f;
  }
  const float scale2 = 0.08838834764831845f * 1.4426950408889634f;  // /sqrt(128)*log2e

  int mstart = half ? 224 : 0;
  int mend   = half ? 416 : 224;            // 6 / 7 steps of 32
  for (int m0 = mstart; m0 < mend; m0 += 32) {
    bf16x8 kf0 = {}, kf1 = {};
    if (quad < 2) {
      int mc0 = m0 + col < LL ? m0 + col : LL - 1;
      int mc1 = m0 + 16 + col < LL ? m0 + 16 + col : LL - 1;
      kf0 = *reinterpret_cast<const bf16x8*>(&kp[mc0 * 16 + quad * 8]);
      kf1 = *reinterpret_cast<const bf16x8*>(&kp[mc1 * 16 + quad * 8]);
    }
    bf16x8 vf;
    {
      int ms = m0 + quad * 8; if (ms > LL - 8) ms = LL - 8;
      vf = *reinterpret_cast<const bf16x8*>(&vp[col * LL + ms]);
    }
    const float4 a4 = *reinterpret_cast<const float4*>(&mb[m0 + quad * 4]);
    const float4 b4 = *reinterpret_cast<const float4*>(&mb[m0 + 16 + quad * 4]);
    float madd[8] = {a4.x, a4.y, a4.z, a4.w, b4.x, b4.y, b4.z, b4.w};
    #pragma unroll
    for (int f = 0; f < 4; f++) {
      f32x4 z = {0.f, 0.f, 0.f, 0.f};
      f32x4 s0 = __builtin_amdgcn_mfma_f32_16x16x32_bf16(kf0, qf[f], z, 0, 0, 0);
      f32x4 s1 = __builtin_amdgcn_mfma_f32_16x16x32_bf16(kf1, qf[f], z, 0, 0, 0);
      float p[8];
      #pragma unroll
      for (int r = 0; r < 4; r++) {
        p[r]     = EXP2F(s0[r] * scale2 + madd[r]);
        p[4 + r] = EXP2F(s1[r] * scale2 + madd[4 + r]);
      }
      float ps = 0.f;
      #pragma unroll
      for (int i = 0; i < 8; i++) ps += p[i];
      psum[f] += ps;
      short* row = &Pl[w][f & 1][col * 40];
      short4 h0 = __builtin_bit_cast(short4, make_uint2(pkbf(p[1], p[0]), pkbf(p[3], p[2])));
      short4 h1 = __builtin_bit_cast(short4, make_uint2(pkbf(p[5], p[4]), pkbf(p[7], p[6])));
      *reinterpret_cast<short4*>(&row[quad * 4])      = h0;
      *reinterpret_cast<short4*>(&row[16 + quad * 4]) = h1;
      bf16x8 pf = *reinterpret_cast<const bf16x8*>(&Pl[w][f & 1][col * 40 + quad * 8]);
      of[f] = __builtin_amdgcn_mfma_f32_16x16x32_bf16(vf, pf, of[f], 0, 0, 0);
    }
  }
  // merge halves: half-1 waves publish partials, half-0 waves combine
  if (half == 1) {
    float* mg = &Mg[pair][lane][0];
    #pragma unroll
    for (int f = 0; f < 4; f++) {
      #pragma unroll
      for (int r = 0; r < 4; r++) mg[f * 4 + r] = of[f][r];
      mg[16 + f] = psum[f];
    }
  }
  __syncthreads();
  if (half == 0 && live) {
    const float* mg = &Mg[pair][lane][0];
    #pragma unroll
    for (int f = 0; f < 4; f++) {
      #pragma unroll
      for (int r = 0; r < 4; r++) of[f][r] += mg[f * 4 + r];
      psum[f] += mg[16 + f];
    }
    #pragma unroll
    for (int f = 0; f < 4; f++) {
      float s = psum[f];
      s += __shfl_xor(s, 16);
      s += __shfl_xor(s, 32);
      float inv = 1.f / s;
      int lf = l0 + f * 16;
      if (lf < LL) {
        #pragma unroll
        for (int r = 0; r < 4; r++)
          ao[base + (size_t)(quad * 4 + r) * LL + lf + col] =
              (unsigned short)f2bf(of[f][r] * inv);
      }
    }
  }
}

// ---------------------------------------------------------------------------
extern "C" void kernel_launch(void* const* d_in, const int* in_sizes, int n_in,
                              void* d_out, int out_size, void* d_ws, size_t ws_size,
                              hipStream_t stream) {
  const float* x    = (const float*)d_in[0];
  const float* mask = (const float*)d_in[1];
  const float* dw_w = (const float*)d_in[2];
  const float* dw_b = (const float*)d_in[3];
  const float* pw_w = (const float*)d_in[4];
  const float* pw_b = (const float*)d_in[5];
  const float* wq   = (const float*)d_in[6];
  const float* bq   = (const float*)d_in[7];
  const float* wk   = (const float*)d_in[8];
  const float* bk   = (const float*)d_in[9];
  const float* wvp  = (const float*)d_in[10];
  const float* bv   = (const float*)d_in[11];
  const float* wo   = (const float*)d_in[12];
  const float* bo   = (const float*)d_in[13];
  const float* fcw  = (const float*)d_in[14];
  const float* fcb  = (const float*)d_in[15];
  const float* lng  = (const float*)d_in[16];
  const float* lnb  = (const float*)d_in[17];
  float* out = (float*)d_out;
  float* ws  = (float*)d_ws;

  float* pstat = ws + 1024;                             // 6*896 f partials
  float* maddb = ws + 1024 + 51200 + 512;               // 64*416 f
  unsigned short* wf = (unsigned short*)(maddb + 64 * 416); // (unused region)
  unsigned short* r0 = wf + 9 * 16384;                  // NBCL bf16 each:
  unsigned short* r1 = r0 + NBCL;
  unsigned short* qt = r1 + NBCL;
  unsigned short* kt = qt + NBCL;
  unsigned short* vbf = kt + NBCL;
  unsigned short* tb = vbf + NBCL;
  int* bar = (int*)(tb + NBCL);                         // 6*64 slots x 32 ints

  hipMemsetAsync(bar, 0, 6 * 64 * 32 * sizeof(int), stream);

  fused_main<<<dim3(7, BN), 512, 0, stream>>>(
      pw_w, wq, wk, wvp, pw_b, dw_b, mask, x, lng, lnb, dw_w,
      bq, bk, bv, pstat, maddb, r0, r1, qt, kt, vbf, bar);
  attn_kernel<<<dim3(512, 4), 256, 0, stream>>>(qt, kt, vbf, maddb, tb);
  wo_fc_fused<<<dim3(7, BN), 512, 0, stream>>>(
      wo, fcw, bo, fcb, tb, r0, r1, lng, lnb, pstat, out, bar);
}

// Round 9
// 248.604 us; speedup vs baseline: 7.1289x; 1.7521x over previous
//
#include <hip/hip_runtime.h>
#include <math.h>

constexpr int BN = 64;
constexpr int CC = 128;
constexpr int LL = 400;
constexpr int DK = 16;
constexpr int KK = 7;
constexpr int CL = CC * LL;              // 51200
constexpr int NBCL = BN * CL;            // 3276800
constexpr float EPSV = 1e-5f;
constexpr float INV_N = 1.0f / (float)CL;
constexpr float BIGL = 1.4427e30f;
constexpr int RW = 96;                   // widened tile (owned 64 + 16 margins)

typedef __attribute__((ext_vector_type(8))) short bf16x8;
typedef __attribute__((ext_vector_type(4))) float f32x4;

#if defined(__has_builtin)
#if __has_builtin(__builtin_amdgcn_exp2f)
#define EXP2F(x) __builtin_amdgcn_exp2f(x)
#endif
#endif
#ifndef EXP2F
#define EXP2F(x) exp2f(x)
#endif

__device__ __forceinline__ short f2bf(float f) {        // RNE
  unsigned u = __builtin_bit_cast(unsigned, f);
  u = (u + 0x7fffu + ((u >> 16) & 1u)) >> 16;
  return (short)u;
}
__device__ __forceinline__ float bf2f(unsigned short u) {
  return __builtin_bit_cast(float, (unsigned)u << 16);
}
__device__ __forceinline__ unsigned pkbf(float hi, float lo) {  // truncate-pack
  return __builtin_amdgcn_perm(__builtin_bit_cast(unsigned, hi),
                               __builtin_bit_cast(unsigned, lo), 0x07060302u);
}

// ---------------------------------------------------------------------------
// LN-stats exchange via agent-scope atomics ONLY (sc-bypassing, coherent at
// the IF coherence point across XCDs) -- NO fences, NO barriers. Rounds 6-8
// showed the fence pair (buffer_wbl2+inv per block per barrier) costs
// ~45-60us; with conv intermediates now LDS-resident there is NO cross-block
// bulk data, so stats scalars are the only communication.
// Layout per (u,bb): 32 floats; [2k,2k+1]=partials of jx=k; int counter at [16].
// Producer ordering: value stores -> s_waitcnt vmcnt(0) (completion at
// coherence point) -> counter add. Consumer: spin relaxed, then load values.
// ---------------------------------------------------------------------------
__device__ __forceinline__ void stats_pub(float* sx, int u, int bb, int jx,
                                          float* red, int tid) {
  if (tid == 0) {
    float a = 0.f, b2 = 0.f;
    #pragma unroll
    for (int w2 = 0; w2 < 8; w2++) { a += red[w2 * 2]; b2 += red[w2 * 2 + 1]; }
    float* base = sx + (u * 64 + bb) * 32;
    __hip_atomic_store(&base[jx * 2], a, __ATOMIC_RELAXED, __HIP_MEMORY_SCOPE_AGENT);
    __hip_atomic_store(&base[jx * 2 + 1], b2, __ATOMIC_RELAXED, __HIP_MEMORY_SCOPE_AGENT);
    asm volatile("s_waitcnt vmcnt(0)" ::: "memory");
    __hip_atomic_fetch_add(reinterpret_cast<int*>(&base[16]), 1,
                           __ATOMIC_RELAXED, __HIP_MEMORY_SCOPE_AGENT);
  }
}
__device__ __forceinline__ void stats_wait(float* sx, int u, int bb,
                                           float* red, int tid,
                                           float& mu, float& rstd) {
  if (tid == 0) {
    float* base = sx + (u * 64 + bb) * 32;
    while (__hip_atomic_load(reinterpret_cast<int*>(&base[16]),
                             __ATOMIC_RELAXED, __HIP_MEMORY_SCOPE_AGENT) < 7)
      __builtin_amdgcn_s_sleep(1);
    float s1 = 0.f, s2 = 0.f;
    #pragma unroll
    for (int k = 0; k < 7; k++) {
      s1 += __hip_atomic_load(&base[k * 2], __ATOMIC_RELAXED, __HIP_MEMORY_SCOPE_AGENT);
      s2 += __hip_atomic_load(&base[k * 2 + 1], __ATOMIC_RELAXED, __HIP_MEMORY_SCOPE_AGENT);
    }
    float m2 = s1 * INV_N;
    red[0] = m2;
    red[1] = rsqrtf(s2 * INV_N - m2 * m2 + EPSV);
  }
  __syncthreads();
  mu = red[0]; rstd = red[1];
  __syncthreads();
}

// ---------------------------------------------------------------------------
// Global-input X staging (64-col tiles) for wo/fc/qkv epilogue-kernels.
// XMODE 0: + LN; XMODE 1: direct copy.
// ---------------------------------------------------------------------------
template<int XMODE>
__device__ __forceinline__ void stage_x(
    short* __restrict__ XsF, const unsigned short* __restrict__ Xb,
    int j0, const float* __restrict__ lng, const float* __restrict__ lnb,
    float mu, float rstd, int tid)
{
  for (int idx = tid; idx < 1024; idx += 512) {
    int c = idx >> 3;
    int l8 = (idx & 7) * 8;
    int col0 = j0 + l8;
    short hv[8];
    bool valid = col0 < LL;               // LL % 8 == 0: all-or-nothing
    int col0c = valid ? col0 : 0;
    const unsigned short* xp = Xb + c * LL + col0c;
    const ushort4 u0 = *reinterpret_cast<const ushort4*>(&xp[0]);
    const ushort4 u1 = *reinterpret_cast<const ushort4*>(&xp[4]);
    unsigned short uu[8] = {u0.x, u0.y, u0.z, u0.w, u1.x, u1.y, u1.z, u1.w};
    if (XMODE == 1) {
      #pragma unroll
      for (int e = 0; e < 8; e++) hv[e] = valid ? (short)uu[e] : (short)0;
    } else {
      const float* gp = lng + c * LL + col0c;
      const float* bp = lnb + c * LL + col0c;
      const float4 g0 = *reinterpret_cast<const float4*>(&gp[0]);
      const float4 g1 = *reinterpret_cast<const float4*>(&gp[4]);
      const float4 b0 = *reinterpret_cast<const float4*>(&bp[0]);
      const float4 b1 = *reinterpret_cast<const float4*>(&bp[4]);
      float gg[8] = {g0.x, g0.y, g0.z, g0.w, g1.x, g1.y, g1.z, g1.w};
      float bbv[8] = {b0.x, b0.y, b0.z, b0.w, b1.x, b1.y, b1.z, b1.w};
      #pragma unroll
      for (int e = 0; e < 8; e++) {
        float v = (bf2f(uu[e]) - mu) * rstd * gg[e] + bbv[e];
        hv[e] = valid ? f2bf(v) : (short)0;
      }
    }
    int t = (l8 >> 4) * 4 + (c >> 5);
    int quad = (c >> 3) & 3;
    int j = c & 7;
    int base = t * 512 + quad * 128 + j;
    int colb = l8 & 15;
    #pragma unroll
    for (int e = 0; e < 8; e++) XsF[base + (colb + e) * 8] = hv[e];
  }
}

// ---------------------------------------------------------------------------
// Global-staged GEMM (N=64) used by wo/fc. W direct from fp32 [o][c].
// ---------------------------------------------------------------------------
template<int XMODE, int OMODE, bool RELU, bool ADDRES, bool STATS>
__device__ __forceinline__ void gemm_gl(
    short* __restrict__ XsF, float* __restrict__ red,
    const float* __restrict__ Wsrc, const unsigned short* __restrict__ Xv,
    const float* __restrict__ bias, const unsigned short* __restrict__ resid,
    const float* __restrict__ lng, const float* __restrict__ lnb,
    float mu, float rstd, void* __restrict__ Yv)
{
  int tid = threadIdx.x;
  int bb = blockIdx.y;
  int j0 = blockIdx.x * 64;
  int w = tid >> 6, lane = tid & 63;
  int o = w * 16 + (lane & 15);
  int cb = (lane >> 4) * 8;
  bf16x8 af[4];
  #pragma unroll
  for (int kt = 0; kt < 4; kt++) {
    const float* wp = Wsrc + o * 128 + kt * 32 + cb;
    const float4 a0 = *reinterpret_cast<const float4*>(wp);
    const float4 a1 = *reinterpret_cast<const float4*>(wp + 4);
    bf16x8 v;
    v[0] = f2bf(a0.x); v[1] = f2bf(a0.y); v[2] = f2bf(a0.z); v[3] = f2bf(a0.w);
    v[4] = f2bf(a1.x); v[5] = f2bf(a1.y); v[6] = f2bf(a1.z); v[7] = f2bf(a1.w);
    af[kt] = v;
  }
  stage_x<XMODE>(XsF, Xv + (size_t)bb * CL, j0, lng, lnb, mu, rstd, tid);
  __syncthreads();
  int col = lane & 15, quad = lane >> 4;
  f32x4 acc[4];
  #pragma unroll
  for (int lf = 0; lf < 4; lf++) acc[lf] = (f32x4){0.f, 0.f, 0.f, 0.f};
  #pragma unroll
  for (int kt = 0; kt < 4; kt++) {
    #pragma unroll
    for (int lf = 0; lf < 4; lf++) {
      bf16x8 bx = *reinterpret_cast<const bf16x8*>(&XsF[(lf * 4 + kt) * 512 + lane * 8]);
      acc[lf] = __builtin_amdgcn_mfma_f32_16x16x32_bf16(af[kt], bx, acc[lf], 0, 0, 0);
    }
  }
  int obase = w * 16;
  float bv[4];
  #pragma unroll
  for (int r = 0; r < 4; r++) bv[r] = bias[obase + quad * 4 + r];
  float lsum = 0.f, lsq = 0.f;
  #pragma unroll
  for (int lf = 0; lf < 4; lf++) {
    if (j0 + lf * 16 < LL) {
      int l = j0 + lf * 16 + col;
      #pragma unroll
      for (int r = 0; r < 4; r++) {
        float v = acc[lf][r] + bv[r];
        if (RELU) v = fmaxf(v, 0.f);
        size_t oidx = (size_t)bb * CL + (size_t)(obase + quad * 4 + r) * LL + l;
        if (ADDRES) v += bf2f(resid[oidx]);
        if (OMODE == 1) {
          unsigned short hb = (unsigned short)f2bf(v);
          ((unsigned short*)Yv)[oidx] = hb;
          if (STATS) { float vf = bf2f(hb); lsum += vf; lsq += vf * vf; }
        } else {
          ((float*)Yv)[oidx] = v;
        }
      }
    }
  }
  if (STATS) {
    #pragma unroll
    for (int off = 32; off > 0; off >>= 1) {
      lsum += __shfl_down(lsum, off);
      lsq  += __shfl_down(lsq, off);
    }
    if (lane == 0) { red[w * 2] = lsum; red[w * 2 + 1] = lsq; }
    __syncthreads();
  }
}

// ---------------------------------------------------------------------------
// FUSED MAIN (grid (7,64) x 512). NO barriers, NO fences. Per block:
//   P0 maddb; P1 x+pos into LDS Raw[128][96] (widened tile) + stats0(atomic)
//   conv1..4: stats_wait -> LN+dwconv staged (LDS->LDS) -> MFMA N=96 ->
//             ReLU+resid in-place in Raw (valid width 88/80/72/64) -> stats
//   conv4 also writes owned 64 cols to r0 (residual for WO dispatch)
//   qkv: stats_wait(4) -> LN stage from Raw -> 3 GEMMs -> qt/kt/vbf
// All conv intermediates LDS-resident; cross-block traffic = stats atomics.
// LDS 48.2KB -> >=2 blocks/CU guaranteed (448 <= 512: no spin deadlock).
// ---------------------------------------------------------------------------
__global__ __launch_bounds__(512, 4) void fused_main(
    const float* __restrict__ pw_w, const float* __restrict__ wq,
    const float* __restrict__ wk, const float* __restrict__ wvp,
    const float* __restrict__ pw_b, const float* __restrict__ dw_b,
    const float* __restrict__ mask, const float* __restrict__ x,
    const float* __restrict__ lng, const float* __restrict__ lnb,
    const float* __restrict__ dw_w,
    const float* __restrict__ bq, const float* __restrict__ bk,
    const float* __restrict__ bvp,
    float* __restrict__ sx, float* __restrict__ maddb,
    unsigned short* __restrict__ r0,
    unsigned short* __restrict__ qt, unsigned short* __restrict__ kt,
    unsigned short* __restrict__ vbf)
{
  __shared__ short Raw[128 * RW];          // 24576 B: raw residual tile (bf16)
  __shared__ short XsF[24 * 512];          // 24576 B: frag-staged tile (N=96)
  __shared__ float red[16];
  int tid = threadIdx.x;
  int jx = blockIdx.x, bb = blockIdx.y;
  int gtid = (bb * 7 + jx) * 512 + tid;
  int g0tile = jx * 64 - 16;               // global col of Raw[.][0]

  // ---- P0: additive attention mask (consumed by attn dispatch) ----
  if (gtid < 26624) {                      // 64 x 416
    int b = gtid / 416, m = gtid - b * 416;
    maddb[gtid] = (m < LL) ? (mask[b * LL + m] - 1.f) * BIGL : -BIGL;
  }

  // ---- P1: Raw = bf16(x + pos_enc) over 96 cols; stats over owned 64 ----
  {
    float s1 = 0.f, s2 = 0.f;
    for (int idx = tid; idx < 1536; idx += 512) {
      int c = idx & 127, grp = idx >> 7;   // 12 groups of 8 cols
      int r = grp * 8;
      float fc2 = (float)c, freq, ph;
      if ((c & 1) == 0) { freq = powf(10000.f, -fc2 / (float)CC);        ph = 0.f; }
      else              { freq = -powf(10000.f, (1.f - fc2) / (float)CC); ph = 1.5707963267948966f; }
      #pragma unroll
      for (int e4 = 0; e4 < 2; e4++) {
        int g = g0tile + r + e4 * 4;
        bool valid4 = (g >= 0) && (g <= LL - 4);
        float4 xv = {0.f, 0.f, 0.f, 0.f};
        if (valid4)
          xv = *reinterpret_cast<const float4*>(&x[((size_t)bb * CC + c) * LL + g]);
        float xe[4] = {xv.x, xv.y, xv.z, xv.w};
        #pragma unroll
        for (int e = 0; e < 4; e++) {
          int rr = r + e4 * 4 + e;
          short hh = 0;
          if (valid4) {
            float p = sinf((float)(g + e) * freq + ph);
            hh = f2bf(xe[e] + p);
          }
          Raw[c * RW + rr] = hh;
          if (rr >= 16 && rr < 80 && (g + e) < LL) {
            float v = bf2f((unsigned short)hh);
            s1 += v; s2 += v * v;
          }
        }
      }
    }
    #pragma unroll
    for (int off = 32; off > 0; off >>= 1) {
      s1 += __shfl_down(s1, off);
      s2 += __shfl_down(s2, off);
    }
    int wv = tid >> 6, lane = tid & 63;
    if (lane == 0) { red[wv * 2] = s1; red[wv * 2 + 1] = s2; }
    __syncthreads();
    stats_pub(sx, 0, bb, jx, red, tid);
  }

  // ---- conv layers 1..4 (all LDS-resident) ----
  int w = tid >> 6, lane = tid & 63;
  int col = lane & 15, quad = lane >> 4;
  int obase = w * 16;
  int wo_ = w * 16 + (lane & 15);          // W-frag row
  int cb = (lane >> 4) * 8;                // W-frag col base
  #pragma unroll 1
  for (int li = 0; li < 4; li++) {
    float mu, rstd;
    stats_wait(sx, li, bb, red, tid, mu, rstd);   // also orders Raw writes
    const float* dww = dw_w + li * CC * KK;
    const float* dwb = dw_b + li * CC;
    // stage LN+dwconv from Raw -> XsF (N=96)
    for (int idx = tid; idx < 1536; idx += 512) {
      int c = idx & 127, grp = idx >> 7;
      int l8 = grp * 8;
      float xn[16];
      const float* gp = lng + c * LL;
      const float* bp = lnb + c * LL;
      #pragma unroll
      for (int g4 = 0; g4 < 4; g4++) {
        int r0w = l8 - 4 + g4 * 4;
        int rc = r0w < 0 ? 0 : (r0w > RW - 4 ? RW - 4 : r0w);
        const ushort4 rv = *reinterpret_cast<const ushort4*>(&Raw[c * RW + rc]);
        unsigned short rr4[4] = {rv.x, rv.y, rv.z, rv.w};
        int gg = g0tile + r0w;
        int ggc = gg < 0 ? 0 : (gg > LL - 4 ? LL - 4 : gg);
        const float4 gv = *reinterpret_cast<const float4*>(&gp[ggc]);
        const float4 bv4 = *reinterpret_cast<const float4*>(&bp[ggc]);
        float ge[4] = {gv.x, gv.y, gv.z, gv.w};
        float be[4] = {bv4.x, bv4.y, bv4.z, bv4.w};
        #pragma unroll
        for (int e = 0; e < 4; e++) {
          int g = gg + e;
          float v = (bf2f(rr4[e]) - mu) * rstd * ge[e] + be[e];
          xn[g4 * 4 + e] = (g >= 0 && g < LL) ? v : 0.f;
        }
      }
      float w7[KK];
      #pragma unroll
      for (int j = 0; j < KK; j++) w7[j] = dww[c * KK + j];
      float dbc = dwb[c];
      short hv[8];
      #pragma unroll
      for (int e = 0; e < 8; e++) {
        float a = 0.f;
        #pragma unroll
        for (int jj = 0; jj < KK; jj++) a += w7[jj] * xn[e + jj + 1];
        hv[e] = f2bf(a + dbc);
      }
      int t = (l8 >> 4) * 4 + (c >> 5);
      int qd = (c >> 3) & 3;
      int j = c & 7;
      int base = t * 512 + qd * 128 + j;
      int colb = l8 & 15;
      #pragma unroll
      for (int e = 0; e < 8; e++) XsF[base + (colb + e) * 8] = hv[e];
    }
    __syncthreads();
    // W frags + MFMA N=96
    const float* Wsrc = pw_w + li * 16384;
    bf16x8 af[4];
    #pragma unroll
    for (int kt = 0; kt < 4; kt++) {
      const float* wp = Wsrc + wo_ * 128 + kt * 32 + cb;
      const float4 a0 = *reinterpret_cast<const float4*>(wp);
      const float4 a1 = *reinterpret_cast<const float4*>(wp + 4);
      bf16x8 v;
      v[0] = f2bf(a0.x); v[1] = f2bf(a0.y); v[2] = f2bf(a0.z); v[3] = f2bf(a0.w);
      v[4] = f2bf(a1.x); v[5] = f2bf(a1.y); v[6] = f2bf(a1.z); v[7] = f2bf(a1.w);
      af[kt] = v;
    }
    f32x4 acc[6];
    #pragma unroll
    for (int lf = 0; lf < 6; lf++) acc[lf] = (f32x4){0.f, 0.f, 0.f, 0.f};
    #pragma unroll
    for (int kt = 0; kt < 4; kt++) {
      #pragma unroll
      for (int lf = 0; lf < 6; lf++) {
        bf16x8 bx = *reinterpret_cast<const bf16x8*>(&XsF[(lf * 4 + kt) * 512 + lane * 8]);
        acc[lf] = __builtin_amdgcn_mfma_f32_16x16x32_bf16(af[kt], bx, acc[lf], 0, 0, 0);
      }
    }
    // epilogue: ReLU + resid, write valid region into Raw in-place
    const float* bias = pw_b + li * CC;
    float bv[4];
    #pragma unroll
    for (int r = 0; r < 4; r++) bv[r] = bias[obase + quad * 4 + r];
    int m = 12 - 4 * li;                   // valid margin: 12,8,4,0
    float lsum = 0.f, lsq = 0.f;
    #pragma unroll
    for (int lf = 0; lf < 6; lf++) {
      int r = lf * 16 + col;
      int g = g0tile + r;
      bool vcol = (r >= 16 - m) && (r < 80 + m) && (g >= 0) && (g < LL);
      #pragma unroll
      for (int rr = 0; rr < 4; rr++) {
        if (vcol) {
          int o = obase + quad * 4 + rr;
          float v = acc[lf][rr] + bv[rr];
          v = fmaxf(v, 0.f);
          v += bf2f((unsigned short)Raw[o * RW + r]);
          unsigned short hb = (unsigned short)f2bf(v);
          Raw[o * RW + r] = (short)hb;
          if (li == 3)                      // final residual -> global r0
            r0[(size_t)bb * CL + (size_t)o * LL + g] = hb;
          if (r >= 16 && r < 80) {
            float vf = bf2f(hb);
            lsum += vf; lsq += vf * vf;
          }
        }
      }
    }
    #pragma unroll
    for (int off = 32; off > 0; off >>= 1) {
      lsum += __shfl_down(lsum, off);
      lsq  += __shfl_down(lsq, off);
    }
    if (lane == 0) { red[w * 2] = lsum; red[w * 2 + 1] = lsq; }
    __syncthreads();
    stats_pub(sx, li + 1, bb, jx, red, tid);
  }

  // ---- QKV: LN stage from Raw owned cols, 3 GEMMs ----
  {
    float mu, rstd;
    stats_wait(sx, 4, bb, red, tid, mu, rstd);
    int j0 = jx * 64;
    for (int idx = tid; idx < 1024; idx += 512) {
      int c = idx >> 3;
      int l8 = (idx & 7) * 8;
      bool valid = (j0 + l8) < LL;
      short hv[8];
      const ushort4 u0 = *reinterpret_cast<const ushort4*>(&Raw[c * RW + 16 + l8]);
      const ushort4 u1 = *reinterpret_cast<const ushort4*>(&Raw[c * RW + 20 + l8]);
      unsigned short uu[8] = {u0.x, u0.y, u0.z, u0.w, u1.x, u1.y, u1.z, u1.w};
      int col0c = valid ? (j0 + l8) : 0;
      const float* gp = lng + c * LL + col0c;
      const float* bp = lnb + c * LL + col0c;
      const float4 g0 = *reinterpret_cast<const float4*>(&gp[0]);
      const float4 g1 = *reinterpret_cast<const float4*>(&gp[4]);
      const float4 b0 = *reinterpret_cast<const float4*>(&bp[0]);
      const float4 b1 = *reinterpret_cast<const float4*>(&bp[4]);
      float gg[8] = {g0.x, g0.y, g0.z, g0.w, g1.x, g1.y, g1.z, g1.w};
      float bbv[8] = {b0.x, b0.y, b0.z, b0.w, b1.x, b1.y, b1.z, b1.w};
      #pragma unroll
      for (int e = 0; e < 8; e++) {
        float v = (bf2f(uu[e]) - mu) * rstd * gg[e] + bbv[e];
        hv[e] = valid ? f2bf(v) : (short)0;
      }
      int t = (l8 >> 4) * 4 + (c >> 5);
      int qd = (c >> 3) & 3;
      int j = c & 7;
      int base = t * 512 + qd * 128 + j;
      int colb = l8 & 15;
      #pragma unroll
      for (int e = 0; e < 8; e++) XsF[base + (colb + e) * 8] = hv[e];
    }
    __syncthreads();
    int j0q = jx * 64;
    #pragma unroll 1
    for (int mm = 0; mm < 3; mm++) {
      const float* Wsrc = (mm == 0) ? wq : (mm == 1) ? wk : wvp;
      const float* bias = (mm == 0) ? bq : (mm == 1) ? bk : bvp;
      bf16x8 af[4];
      #pragma unroll
      for (int kt2 = 0; kt2 < 4; kt2++) {
        const float* wp = Wsrc + wo_ * 128 + kt2 * 32 + cb;
        const float4 a0 = *reinterpret_cast<const float4*>(wp);
        const float4 a1 = *reinterpret_cast<const float4*>(wp + 4);
        bf16x8 v;
        v[0] = f2bf(a0.x); v[1] = f2bf(a0.y); v[2] = f2bf(a0.z); v[3] = f2bf(a0.w);
        v[4] = f2bf(a1.x); v[5] = f2bf(a1.y); v[6] = f2bf(a1.z); v[7] = f2bf(a1.w);
        af[kt2] = v;
      }
      f32x4 acc[4];
      #pragma unroll
      for (int lf = 0; lf < 4; lf++) acc[lf] = (f32x4){0.f, 0.f, 0.f, 0.f};
      #pragma unroll
      for (int kt2 = 0; kt2 < 4; kt2++) {
        #pragma unroll
        for (int lf = 0; lf < 4; lf++) {
          bf16x8 bx = *reinterpret_cast<const bf16x8*>(&XsF[(lf * 4 + kt2) * 512 + lane * 8]);
          acc[lf] = __builtin_amdgcn_mfma_f32_16x16x32_bf16(af[kt2], bx, acc[lf], 0, 0, 0);
        }
      }
      float bv4[4];
      #pragma unroll
      for (int r = 0; r < 4; r++) bv4[r] = bias[obase + quad * 4 + r];
      if (mm < 2) {
        unsigned short* dst = (mm == 0) ? qt : kt;
        #pragma unroll
        for (int lf = 0; lf < 4; lf++) {
          if (j0q + lf * 16 < LL) {
            int l = j0q + lf * 16 + col;
            short4 hv4 = {f2bf(acc[lf][0] + bv4[0]), f2bf(acc[lf][1] + bv4[1]),
                          f2bf(acc[lf][2] + bv4[2]), f2bf(acc[lf][3] + bv4[3])};
            *reinterpret_cast<short4*>(
                &dst[(((size_t)bb * 8 + w) * LL + l) * 16 + quad * 4]) = hv4;
          }
        }
      } else {
        #pragma unroll
        for (int lf = 0; lf < 4; lf++) {
          if (j0q + lf * 16 < LL) {
            int l = j0q + lf * 16 + col;
            #pragma unroll
            for (int r = 0; r < 4; r++) {
              float v = acc[lf][r] + bv4[r];
              vbf[(size_t)bb * CL + (size_t)(obase + quad * 4 + r) * LL + l] =
                  (unsigned short)f2bf(v);
            }
          }
        }
      }
    }
  }
}

// ---------------------------------------------------------------------------
// WO + FC fused (stats5 via atomics; no barrier/fence — fc reads only its
// own block's r1 writes, same L2).
// ---------------------------------------------------------------------------
__global__ __launch_bounds__(512, 4) void wo_fc_fused(
    const float* __restrict__ wo, const float* __restrict__ fcw,
    const float* __restrict__ bo, const float* __restrict__ fcb,
    const unsigned short* __restrict__ tb,
    const unsigned short* __restrict__ r0, unsigned short* __restrict__ r1,
    const float* __restrict__ lng, const float* __restrict__ lnb,
    float* __restrict__ sx, float* __restrict__ out)
{
  __shared__ short XsF[16 * 512];
  __shared__ float red[16];
  int tid = threadIdx.x;
  int jx = blockIdx.x, bb = blockIdx.y;
  // WO projection + residual -> r1 (bf16), stats5 partials
  gemm_gl<1, 1, false, true, true>(XsF, red, wo, tb, bo, r0,
                                   nullptr, nullptr, 0.f, 0.f, r1);
  stats_pub(sx, 5, bb, jx, red, tid);
  float mu, rstd;
  stats_wait(sx, 5, bb, red, tid, mu, rstd);
  // FC (LN on load) + ReLU + residual -> out (fp32)
  gemm_gl<0, 0, true, true, false>(XsF, red, fcw, r1, fcb, r1,
                                   lng, lnb, mu, rstd, out);
}

// ---------------------------------------------------------------------------
// attention: 4 waves/block = 2 l-tiles x 2 m-halves (static-max softmax
// partials combine additively). 16-row f-level double-buffered P per wave.
// ---------------------------------------------------------------------------
__global__ __launch_bounds__(256, 4) void attn_kernel(
    const unsigned short* __restrict__ qt, const unsigned short* __restrict__ kt,
    const unsigned short* __restrict__ vb, const float* __restrict__ maddb,
    unsigned short* __restrict__ ao)
{
  __shared__ short Pl[4][2][640];           // 10240 B: per-wave f-level dbuf
  __shared__ float Mg[2][64][20];           // 10240 B: merge of[16]+psum[4]
  int bh = blockIdx.x;
  int b = bh >> 3, h = bh & 7;
  int w = threadIdx.x >> 6, lane = threadIdx.x & 63;
  int pair = w >> 1, half = w & 1;
  int tile = blockIdx.y * 2 + pair;
  bool live = tile < 7;
  int tile_c = live ? tile : 6;
  int col = lane & 15, quad = lane >> 4;
  int l0 = tile_c * 64;
  size_t trow = ((size_t)b * 8 + h) * LL;
  size_t base = ((size_t)b * CC + h * DK) * LL;
  const unsigned short* qp = qt + trow * 16;
  const unsigned short* kp = kt + trow * 16;
  const unsigned short* vp = vb + base;
  const float* mb = maddb + (size_t)b * 416;

  bf16x8 qf[4];
  #pragma unroll
  for (int f = 0; f < 4; f++) {
    bf16x8 v = {};
    if (quad < 2) {
      int l = l0 + f * 16 + col; int lc = l < LL ? l : LL - 1;
      v = *reinterpret_cast<const bf16x8*>(&qp[lc * 16 + quad * 8]);
    }
    qf[f] = v;
  }
  f32x4 of[4];
  float psum[4];
  #pragma unroll
  for (int f = 0; f < 4; f++) {
    of[f] = (f32x4){0.f, 0.f, 0.f, 0.f};
    psum[f] = 0.f;
  }
  const float scale2 = 0.08838834764831845f * 1.4426950408889634f;  // /sqrt(128)*log2e

  int mstart = half ? 224 : 0;
  int mend   = half ? 416 : 224;            // 6 / 7 steps of 32
  for (int m0 = mstart; m0 < mend; m0 += 32) {
    bf16x8 kf0 = {}, kf1 = {};
    if (quad < 2) {
      int mc0 = m0 + col < LL ? m0 + col : LL - 1;
      int mc1 = m0 + 16 + col < LL ? m0 + 16 + col : LL - 1;
      kf0 = *reinterpret_cast<const bf16x8*>(&kp[mc0 * 16 + quad * 8]);
      kf1 = *reinterpret_cast<const bf16x8*>(&kp[mc1 * 16 + quad * 8]);
    }
    bf16x8 vf;
    {
      int ms = m0 + quad * 8; if (ms > LL - 8) ms = LL - 8;
      vf = *reinterpret_cast<const bf16x8*>(&vp[col * LL + ms]);
    }
    const float4 a4 = *reinterpret_cast<const float4*>(&mb[m0 + quad * 4]);
    const float4 b4 = *reinterpret_cast<const float4*>(&mb[m0 + 16 + quad * 4]);
    float madd[8] = {a4.x, a4.y, a4.z, a4.w, b4.x, b4.y, b4.z, b4.w};
    #pragma unroll
    for (int f = 0; f < 4; f++) {
      f32x4 z = {0.f, 0.f, 0.f, 0.f};
      f32x4 s0 = __builtin_amdgcn_mfma_f32_16x16x32_bf16(kf0, qf[f], z, 0, 0, 0);
      f32x4 s1 = __builtin_amdgcn_mfma_f32_16x16x32_bf16(kf1, qf[f], z, 0, 0, 0);
      float p[8];
      #pragma unroll
      for (int r = 0; r < 4; r++) {
        p[r]     = EXP2F(s0[r] * scale2 + madd[r]);
        p[4 + r] = EXP2F(s1[r] * scale2 + madd[4 + r]);
      }
      float ps = 0.f;
      #pragma unroll
      for (int i = 0; i < 8; i++) ps += p[i];
      psum[f] += ps;
      short* row = &Pl[w][f & 1][col * 40];
      short4 h0 = __builtin_bit_cast(short4, make_uint2(pkbf(p[1], p[0]), pkbf(p[3], p[2])));
      short4 h1 = __builtin_bit_cast(short4, make_uint2(pkbf(p[5], p[4]), pkbf(p[7], p[6])));
      *reinterpret_cast<short4*>(&row[quad * 4])      = h0;
      *reinterpret_cast<short4*>(&row[16 + quad * 4]) = h1;
      bf16x8 pf = *reinterpret_cast<const bf16x8*>(&Pl[w][f & 1][col * 40 + quad * 8]);
      of[f] = __builtin_amdgcn_mfma_f32_16x16x32_bf16(vf, pf, of[f], 0, 0, 0);
    }
  }
  // merge halves: half-1 waves publish partials, half-0 waves combine
  if (half == 1) {
    float* mg = &Mg[pair][lane][0];
    #pragma unroll
    for (int f = 0; f < 4; f++) {
      #pragma unroll
      for (int r = 0; r < 4; r++) mg[f * 4 + r] = of[f][r];
      mg[16 + f] = psum[f];
    }
  }
  __syncthreads();
  if (half == 0 && live) {
    const float* mg = &Mg[pair][lane][0];
    #pragma unroll
    for (int f = 0; f < 4; f++) {
      #pragma unroll
      for (int r = 0; r < 4; r++) of[f][r] += mg[f * 4 + r];
      psum[f] += mg[16 + f];
    }
    #pragma unroll
    for (int f = 0; f < 4; f++) {
      float s = psum[f];
      s += __shfl_xor(s, 16);
      s += __shfl_xor(s, 32);
      float inv = 1.f / s;
      int lf = l0 + f * 16;
      if (lf < LL) {
        #pragma unroll
        for (int r = 0; r < 4; r++)
          ao[base + (size_t)(quad * 4 + r) * LL + lf + col] =
              (unsigned short)f2bf(of[f][r] * inv);
      }
    }
  }
}

// ---------------------------------------------------------------------------
extern "C" void kernel_launch(void* const* d_in, const int* in_sizes, int n_in,
                              void* d_out, int out_size, void* d_ws, size_t ws_size,
                              hipStream_t stream) {
  const float* x    = (const float*)d_in[0];
  const float* mask = (const float*)d_in[1];
  const float* dw_w = (const float*)d_in[2];
  const float* dw_b = (const float*)d_in[3];
  const float* pw_w = (const float*)d_in[4];
  const float* pw_b = (const float*)d_in[5];
  const float* wq   = (const float*)d_in[6];
  const float* bq   = (const float*)d_in[7];
  const float* wk   = (const float*)d_in[8];
  const float* bk   = (const float*)d_in[9];
  const float* wvp  = (const float*)d_in[10];
  const float* bv   = (const float*)d_in[11];
  const float* wo   = (const float*)d_in[12];
  const float* bo   = (const float*)d_in[13];
  const float* fcw  = (const float*)d_in[14];
  const float* fcb  = (const float*)d_in[15];
  const float* lng  = (const float*)d_in[16];
  const float* lnb  = (const float*)d_in[17];
  float* out = (float*)d_out;
  float* ws  = (float*)d_ws;

  float* sx    = ws;                                    // 6*64*32 f atomics
  float* maddb = ws + 6 * 64 * 32;                      // 64*416 f
  unsigned short* r0 = (unsigned short*)(maddb + 64 * 416);
  unsigned short* r1 = r0 + NBCL;
  unsigned short* qt = r1 + NBCL;
  unsigned short* kt = qt + NBCL;
  unsigned short* vbf = kt + NBCL;
  unsigned short* tb = vbf + NBCL;

  hipMemsetAsync(sx, 0, 6 * 64 * 32 * sizeof(float), stream);

  fused_main<<<dim3(7, BN), 512, 0, stream>>>(
      pw_w, wq, wk, wvp, pw_b, dw_b, mask, x, lng, lnb, dw_w,
      bq, bk, bv, sx, maddb, r0, qt, kt, vbf);
  attn_kernel<<<dim3(512, 4), 256, 0, stream>>>(qt, kt, vbf, maddb, tb);
  wo_fc_fused<<<dim3(7, BN), 512, 0, stream>>>(
      wo, fcw, bo, fcb, tb, r0, r1, lng, lnb, sx, out);
}

// Round 10
// 240.726 us; speedup vs baseline: 7.3622x; 1.0327x over previous
//
#include <hip/hip_runtime.h>
#include <math.h>

constexpr int BN = 64;
constexpr int CC = 128;
constexpr int LL = 400;
constexpr int DK = 16;
constexpr int KK = 7;
constexpr int CL = CC * LL;              // 51200
constexpr int NBCL = BN * CL;            // 3276800
constexpr float EPSV = 1e-5f;
constexpr float INV_N = 1.0f / (float)CL;
constexpr float BIGL = 1.4427e30f;
constexpr int RW = 100;                  // 96 cols + 4 pad: row stride 50 dwords
                                         // == 18 mod 32 (gcd 2 -> <=4-way) vs
                                         // 96's 48==16 mod 32 (16-way, 13M conflicts)

typedef __attribute__((ext_vector_type(8))) short bf16x8;
typedef __attribute__((ext_vector_type(4))) float f32x4;

#if defined(__has_builtin)
#if __has_builtin(__builtin_amdgcn_exp2f)
#define EXP2F(x) __builtin_amdgcn_exp2f(x)
#endif
#endif
#ifndef EXP2F
#define EXP2F(x) exp2f(x)
#endif

__device__ __forceinline__ short f2bf(float f) {        // RNE
  unsigned u = __builtin_bit_cast(unsigned, f);
  u = (u + 0x7fffu + ((u >> 16) & 1u)) >> 16;
  return (short)u;
}
__device__ __forceinline__ float bf2f(unsigned short u) {
  return __builtin_bit_cast(float, (unsigned)u << 16);
}
__device__ __forceinline__ unsigned pkbf(float hi, float lo) {  // truncate-pack
  return __builtin_amdgcn_perm(__builtin_bit_cast(unsigned, hi),
                               __builtin_bit_cast(unsigned, lo), 0x07060302u);
}

// ---------------------------------------------------------------------------
// LN-stats exchange via agent-scope atomics ONLY -- no fences, no barriers
// (proven round 9: fused_main 274->126us). Producer: atomic value stores ->
// s_waitcnt vmcnt(0) -> atomic counter add. Consumer: relaxed spin.
// ---------------------------------------------------------------------------
__device__ __forceinline__ void stats_pub(float* sx, int u, int bb, int jx,
                                          float* red, int tid) {
  if (tid == 0) {
    float a = 0.f, b2 = 0.f;
    #pragma unroll
    for (int w2 = 0; w2 < 8; w2++) { a += red[w2 * 2]; b2 += red[w2 * 2 + 1]; }
    float* base = sx + (u * 64 + bb) * 32;
    __hip_atomic_store(&base[jx * 2], a, __ATOMIC_RELAXED, __HIP_MEMORY_SCOPE_AGENT);
    __hip_atomic_store(&base[jx * 2 + 1], b2, __ATOMIC_RELAXED, __HIP_MEMORY_SCOPE_AGENT);
    asm volatile("s_waitcnt vmcnt(0)" ::: "memory");
    __hip_atomic_fetch_add(reinterpret_cast<int*>(&base[16]), 1,
                           __ATOMIC_RELAXED, __HIP_MEMORY_SCOPE_AGENT);
  }
}
__device__ __forceinline__ void stats_wait(float* sx, int u, int bb,
                                           float* red, int tid,
                                           float& mu, float& rstd) {
  if (tid == 0) {
    float* base = sx + (u * 64 + bb) * 32;
    while (__hip_atomic_load(reinterpret_cast<int*>(&base[16]),
                             __ATOMIC_RELAXED, __HIP_MEMORY_SCOPE_AGENT) < 7)
      __builtin_amdgcn_s_sleep(1);
    float s1 = 0.f, s2 = 0.f;
    #pragma unroll
    for (int k = 0; k < 7; k++) {
      s1 += __hip_atomic_load(&base[k * 2], __ATOMIC_RELAXED, __HIP_MEMORY_SCOPE_AGENT);
      s2 += __hip_atomic_load(&base[k * 2 + 1], __ATOMIC_RELAXED, __HIP_MEMORY_SCOPE_AGENT);
    }
    float m2 = s1 * INV_N;
    red[0] = m2;
    red[1] = rsqrtf(s2 * INV_N - m2 * m2 + EPSV);
  }
  __syncthreads();
  mu = red[0]; rstd = red[1];
  __syncthreads();
}

// ---------------------------------------------------------------------------
// FUSED MAIN (grid (7,64) x 512). Identical to round 9 except RW=100 padding.
//   P0 maddb; P1 x+pos -> LDS Raw[128][RW] + stats0(atomic)
//   conv1..4: stats_wait -> LN+dwconv (LDS->LDS) -> MFMA N=96 -> ReLU+resid
//   in-place (valid 88/80/72/64); conv4 writes owned 64 cols to r0
//   qkv: stats_wait(4) -> LN stage from Raw -> 3 GEMMs -> qt/kt/vbf
// ---------------------------------------------------------------------------
__global__ __launch_bounds__(512, 4) void fused_main(
    const float* __restrict__ pw_w, const float* __restrict__ wq,
    const float* __restrict__ wk, const float* __restrict__ wvp,
    const float* __restrict__ pw_b, const float* __restrict__ dw_b,
    const float* __restrict__ mask, const float* __restrict__ x,
    const float* __restrict__ lng, const float* __restrict__ lnb,
    const float* __restrict__ dw_w,
    const float* __restrict__ bq, const float* __restrict__ bk,
    const float* __restrict__ bvp,
    float* __restrict__ sx, float* __restrict__ maddb,
    unsigned short* __restrict__ r0,
    unsigned short* __restrict__ qt, unsigned short* __restrict__ kt,
    unsigned short* __restrict__ vbf)
{
  __shared__ short Raw[128 * RW];          // 25600 B: raw residual tile (bf16)
  __shared__ short XsF[24 * 512];          // 24576 B: frag-staged tile (N=96)
  __shared__ float red[16];
  int tid = threadIdx.x;
  int jx = blockIdx.x, bb = blockIdx.y;
  int gtid = (bb * 7 + jx) * 512 + tid;
  int g0tile = jx * 64 - 16;               // global col of Raw[.][0]

  // ---- P0: additive attention mask (consumed by attn dispatch) ----
  if (gtid < 26624) {                      // 64 x 416
    int b = gtid / 416, m = gtid - b * 416;
    maddb[gtid] = (m < LL) ? (mask[b * LL + m] - 1.f) * BIGL : -BIGL;
  }

  // ---- P1: Raw = bf16(x + pos_enc) over 96 cols; stats over owned 64 ----
  {
    float s1 = 0.f, s2 = 0.f;
    for (int idx = tid; idx < 1536; idx += 512) {
      int c = idx & 127, grp = idx >> 7;   // 12 groups of 8 cols
      int r = grp * 8;
      float fc2 = (float)c, freq, ph;
      if ((c & 1) == 0) { freq = powf(10000.f, -fc2 / (float)CC);        ph = 0.f; }
      else              { freq = -powf(10000.f, (1.f - fc2) / (float)CC); ph = 1.5707963267948966f; }
      #pragma unroll
      for (int e4 = 0; e4 < 2; e4++) {
        int g = g0tile + r + e4 * 4;
        bool valid4 = (g >= 0) && (g <= LL - 4);
        float4 xv = {0.f, 0.f, 0.f, 0.f};
        if (valid4)
          xv = *reinterpret_cast<const float4*>(&x[((size_t)bb * CC + c) * LL + g]);
        float xe[4] = {xv.x, xv.y, xv.z, xv.w};
        #pragma unroll
        for (int e = 0; e < 4; e++) {
          int rr = r + e4 * 4 + e;
          short hh = 0;
          if (valid4) {
            float p = sinf((float)(g + e) * freq + ph);
            hh = f2bf(xe[e] + p);
          }
          Raw[c * RW + rr] = hh;
          if (rr >= 16 && rr < 80 && (g + e) < LL) {
            float v = bf2f((unsigned short)hh);
            s1 += v; s2 += v * v;
          }
        }
      }
    }
    #pragma unroll
    for (int off = 32; off > 0; off >>= 1) {
      s1 += __shfl_down(s1, off);
      s2 += __shfl_down(s2, off);
    }
    int wv = tid >> 6, lane = tid & 63;
    if (lane == 0) { red[wv * 2] = s1; red[wv * 2 + 1] = s2; }
    __syncthreads();
    stats_pub(sx, 0, bb, jx, red, tid);
  }

  // ---- conv layers 1..4 (all LDS-resident) ----
  int w = tid >> 6, lane = tid & 63;
  int col = lane & 15, quad = lane >> 4;
  int obase = w * 16;
  int wo_ = w * 16 + (lane & 15);          // W-frag row
  int cb = (lane >> 4) * 8;                // W-frag col base
  #pragma unroll 1
  for (int li = 0; li < 4; li++) {
    float mu, rstd;
    stats_wait(sx, li, bb, red, tid, mu, rstd);   // also orders Raw writes
    const float* dww = dw_w + li * CC * KK;
    const float* dwb = dw_b + li * CC;
    // stage LN+dwconv from Raw -> XsF (N=96)
    for (int idx = tid; idx < 1536; idx += 512) {
      int c = idx & 127, grp = idx >> 7;
      int l8 = grp * 8;
      float xn[16];
      const float* gp = lng + c * LL;
      const float* bp = lnb + c * LL;
      #pragma unroll
      for (int g4 = 0; g4 < 4; g4++) {
        int r0w = l8 - 4 + g4 * 4;
        int rc = r0w < 0 ? 0 : (r0w > 96 - 4 ? 96 - 4 : r0w);
        const ushort4 rv = *reinterpret_cast<const ushort4*>(&Raw[c * RW + rc]);
        unsigned short rr4[4] = {rv.x, rv.y, rv.z, rv.w};
        int gg = g0tile + r0w;
        int ggc = gg < 0 ? 0 : (gg > LL - 4 ? LL - 4 : gg);
        const float4 gv = *reinterpret_cast<const float4*>(&gp[ggc]);
        const float4 bv4 = *reinterpret_cast<const float4*>(&bp[ggc]);
        float ge[4] = {gv.x, gv.y, gv.z, gv.w};
        float be[4] = {bv4.x, bv4.y, bv4.z, bv4.w};
        #pragma unroll
        for (int e = 0; e < 4; e++) {
          int g = gg + e;
          float v = (bf2f(rr4[e]) - mu) * rstd * ge[e] + be[e];
          xn[g4 * 4 + e] = (g >= 0 && g < LL) ? v : 0.f;
        }
      }
      float w7[KK];
      #pragma unroll
      for (int j = 0; j < KK; j++) w7[j] = dww[c * KK + j];
      float dbc = dwb[c];
      short hv[8];
      #pragma unroll
      for (int e = 0; e < 8; e++) {
        float a = 0.f;
        #pragma unroll
        for (int jj = 0; jj < KK; jj++) a += w7[jj] * xn[e + jj + 1];
        hv[e] = f2bf(a + dbc);
      }
      int t = (l8 >> 4) * 4 + (c >> 5);
      int qd = (c >> 3) & 3;
      int j = c & 7;
      int base = t * 512 + qd * 128 + j;
      int colb = l8 & 15;
      #pragma unroll
      for (int e = 0; e < 8; e++) XsF[base + (colb + e) * 8] = hv[e];
    }
    __syncthreads();
    // W frags + MFMA N=96
    const float* Wsrc = pw_w + li * 16384;
    bf16x8 af[4];
    #pragma unroll
    for (int kt = 0; kt < 4; kt++) {
      const float* wp = Wsrc + wo_ * 128 + kt * 32 + cb;
      const float4 a0 = *reinterpret_cast<const float4*>(wp);
      const float4 a1 = *reinterpret_cast<const float4*>(wp + 4);
      bf16x8 v;
      v[0] = f2bf(a0.x); v[1] = f2bf(a0.y); v[2] = f2bf(a0.z); v[3] = f2bf(a0.w);
      v[4] = f2bf(a1.x); v[5] = f2bf(a1.y); v[6] = f2bf(a1.z); v[7] = f2bf(a1.w);
      af[kt] = v;
    }
    f32x4 acc[6];
    #pragma unroll
    for (int lf = 0; lf < 6; lf++) acc[lf] = (f32x4){0.f, 0.f, 0.f, 0.f};
    #pragma unroll
    for (int kt = 0; kt < 4; kt++) {
      #pragma unroll
      for (int lf = 0; lf < 6; lf++) {
        bf16x8 bx = *reinterpret_cast<const bf16x8*>(&XsF[(lf * 4 + kt) * 512 + lane * 8]);
        acc[lf] = __builtin_amdgcn_mfma_f32_16x16x32_bf16(af[kt], bx, acc[lf], 0, 0, 0);
      }
    }
    // epilogue: ReLU + resid, write valid region into Raw in-place
    const float* bias = pw_b + li * CC;
    float bv[4];
    #pragma unroll
    for (int r = 0; r < 4; r++) bv[r] = bias[obase + quad * 4 + r];
    int m = 12 - 4 * li;                   // valid margin: 12,8,4,0
    float lsum = 0.f, lsq = 0.f;
    #pragma unroll
    for (int lf = 0; lf < 6; lf++) {
      int r = lf * 16 + col;
      int g = g0tile + r;
      bool vcol = (r >= 16 - m) && (r < 80 + m) && (g >= 0) && (g < LL);
      #pragma unroll
      for (int rr = 0; rr < 4; rr++) {
        if (vcol) {
          int o = obase + quad * 4 + rr;
          float v = acc[lf][rr] + bv[rr];
          v = fmaxf(v, 0.f);
          v += bf2f((unsigned short)Raw[o * RW + r]);
          unsigned short hb = (unsigned short)f2bf(v);
          Raw[o * RW + r] = (short)hb;
          if (li == 3)                      // final residual -> global r0
            r0[(size_t)bb * CL + (size_t)o * LL + g] = hb;
          if (r >= 16 && r < 80) {
            float vf = bf2f(hb);
            lsum += vf; lsq += vf * vf;
          }
        }
      }
    }
    #pragma unroll
    for (int off = 32; off > 0; off >>= 1) {
      lsum += __shfl_down(lsum, off);
      lsq  += __shfl_down(lsq, off);
    }
    if (lane == 0) { red[w * 2] = lsum; red[w * 2 + 1] = lsq; }
    __syncthreads();
    stats_pub(sx, li + 1, bb, jx, red, tid);
  }

  // ---- QKV: LN stage from Raw owned cols, 3 GEMMs ----
  {
    float mu, rstd;
    stats_wait(sx, 4, bb, red, tid, mu, rstd);
    int j0 = jx * 64;
    for (int idx = tid; idx < 1024; idx += 512) {
      int c = idx >> 3;
      int l8 = (idx & 7) * 8;
      bool valid = (j0 + l8) < LL;
      short hv[8];
      const ushort4 u0 = *reinterpret_cast<const ushort4*>(&Raw[c * RW + 16 + l8]);
      const ushort4 u1 = *reinterpret_cast<const ushort4*>(&Raw[c * RW + 20 + l8]);
      unsigned short uu[8] = {u0.x, u0.y, u0.z, u0.w, u1.x, u1.y, u1.z, u1.w};
      int col0c = valid ? (j0 + l8) : 0;
      const float* gp = lng + c * LL + col0c;
      const float* bp = lnb + c * LL + col0c;
      const float4 g0 = *reinterpret_cast<const float4*>(&gp[0]);
      const float4 g1 = *reinterpret_cast<const float4*>(&gp[4]);
      const float4 b0 = *reinterpret_cast<const float4*>(&bp[0]);
      const float4 b1 = *reinterpret_cast<const float4*>(&bp[4]);
      float gg[8] = {g0.x, g0.y, g0.z, g0.w, g1.x, g1.y, g1.z, g1.w};
      float bbv[8] = {b0.x, b0.y, b0.z, b0.w, b1.x, b1.y, b1.z, b1.w};
      #pragma unroll
      for (int e = 0; e < 8; e++) {
        float v = (bf2f(uu[e]) - mu) * rstd * gg[e] + bbv[e];
        hv[e] = valid ? f2bf(v) : (short)0;
      }
      int t = (l8 >> 4) * 4 + (c >> 5);
      int qd = (c >> 3) & 3;
      int j = c & 7;
      int base = t * 512 + qd * 128 + j;
      int colb = l8 & 15;
      #pragma unroll
      for (int e = 0; e < 8; e++) XsF[base + (colb + e) * 8] = hv[e];
    }
    __syncthreads();
    int j0q = jx * 64;
    #pragma unroll 1
    for (int mm = 0; mm < 3; mm++) {
      const float* Wsrc = (mm == 0) ? wq : (mm == 1) ? wk : wvp;
      const float* bias = (mm == 0) ? bq : (mm == 1) ? bk : bvp;
      bf16x8 af[4];
      #pragma unroll
      for (int kt2 = 0; kt2 < 4; kt2++) {
        const float* wp = Wsrc + wo_ * 128 + kt2 * 32 + cb;
        const float4 a0 = *reinterpret_cast<const float4*>(wp);
        const float4 a1 = *reinterpret_cast<const float4*>(wp + 4);
        bf16x8 v;
        v[0] = f2bf(a0.x); v[1] = f2bf(a0.y); v[2] = f2bf(a0.z); v[3] = f2bf(a0.w);
        v[4] = f2bf(a1.x); v[5] = f2bf(a1.y); v[6] = f2bf(a1.z); v[7] = f2bf(a1.w);
        af[kt2] = v;
      }
      f32x4 acc[4];
      #pragma unroll
      for (int lf = 0; lf < 4; lf++) acc[lf] = (f32x4){0.f, 0.f, 0.f, 0.f};
      #pragma unroll
      for (int kt2 = 0; kt2 < 4; kt2++) {
        #pragma unroll
        for (int lf = 0; lf < 4; lf++) {
          bf16x8 bx = *reinterpret_cast<const bf16x8*>(&XsF[(lf * 4 + kt2) * 512 + lane * 8]);
          acc[lf] = __builtin_amdgcn_mfma_f32_16x16x32_bf16(af[kt2], bx, acc[lf], 0, 0, 0);
        }
      }
      float bv4[4];
      #pragma unroll
      for (int r = 0; r < 4; r++) bv4[r] = bias[obase + quad * 4 + r];
      if (mm < 2) {
        unsigned short* dst = (mm == 0) ? qt : kt;
        #pragma unroll
        for (int lf = 0; lf < 4; lf++) {
          if (j0q + lf * 16 < LL) {
            int l = j0q + lf * 16 + col;
            short4 hv4 = {f2bf(acc[lf][0] + bv4[0]), f2bf(acc[lf][1] + bv4[1]),
                          f2bf(acc[lf][2] + bv4[2]), f2bf(acc[lf][3] + bv4[3])};
            *reinterpret_cast<short4*>(
                &dst[(((size_t)bb * 8 + w) * LL + l) * 16 + quad * 4]) = hv4;
          }
        }
      } else {
        #pragma unroll
        for (int lf = 0; lf < 4; lf++) {
          if (j0q + lf * 16 < LL) {
            int l = j0q + lf * 16 + col;
            #pragma unroll
            for (int r = 0; r < 4; r++) {
              float v = acc[lf][r] + bv4[r];
              vbf[(size_t)bb * CL + (size_t)(obase + quad * 4 + r) * LL + l] =
                  (unsigned short)f2bf(v);
            }
          }
        }
      }
    }
  }
}

// ---------------------------------------------------------------------------
// ATTN + WO + FC fused (grid (7,64) x 512 = 8 waves). Wave w = head h,
// block (jx,bb) = l-tile jx of batch bb. Each wave runs the FULL m-loop
// (13 steps) for its (b,h,tile) -- no half-split/merge needed. Attn output
// written directly into XsF in MFMA frag layout (c = h*16+quad*4+r,
// l_local = f*16+col) -> WO GEMM consumes it with ZERO staging. r1 lives in
// LDS R1[128][68] (68 pad: stride 34 dwords == 2 mod 32, <=4-way). stats5
// via the proven atomic pattern; fc reads only block-local data.
// Removes: 1 dispatch boundary, ao/tb global round-trip, r1 round-trip,
// wo staging pass.
// ---------------------------------------------------------------------------
__global__ __launch_bounds__(512, 4) void attn_wo_fc(
    const unsigned short* __restrict__ qt, const unsigned short* __restrict__ kt,
    const unsigned short* __restrict__ vbf, const float* __restrict__ maddb,
    const unsigned short* __restrict__ r0,
    const float* __restrict__ wo, const float* __restrict__ fcw,
    const float* __restrict__ bo, const float* __restrict__ fcb,
    const float* __restrict__ lng, const float* __restrict__ lnb,
    float* __restrict__ sx, float* __restrict__ out)
{
  __shared__ short Pl[8][2][640];          // 20480 B: per-wave P dbuf
  __shared__ short XsF[16 * 512];          // 16384 B: attn-out frag tile
  __shared__ short R1[128 * 68];           // 17408 B: wo+resid tile (bf16)
  __shared__ float red[16];
  int tid = threadIdx.x;
  int jx = blockIdx.x, bb = blockIdx.y;
  int w = tid >> 6, lane = tid & 63;
  int h = w;                               // one head per wave
  int col = lane & 15, quad = lane >> 4;
  int l0 = jx * 64;
  size_t trow = ((size_t)bb * 8 + h) * LL;
  const unsigned short* qp = qt + trow * 16;
  const unsigned short* kp = kt + trow * 16;
  const unsigned short* vp = vbf + ((size_t)bb * CC + h * DK) * LL;
  const float* mb = maddb + (size_t)bb * 416;
  const float scale2 = 0.08838834764831845f * 1.4426950408889634f;  // /sqrt(128)*log2e

  // ---- attention ----
  bf16x8 qf[4];
  #pragma unroll
  for (int f = 0; f < 4; f++) {
    bf16x8 v = {};
    if (quad < 2) {
      int l = l0 + f * 16 + col; int lc = l < LL ? l : LL - 1;
      v = *reinterpret_cast<const bf16x8*>(&qp[lc * 16 + quad * 8]);
    }
    qf[f] = v;
  }
  f32x4 of[4];
  float psum[4];
  #pragma unroll
  for (int f = 0; f < 4; f++) {
    of[f] = (f32x4){0.f, 0.f, 0.f, 0.f};
    psum[f] = 0.f;
  }
  for (int m0 = 0; m0 < 416; m0 += 32) {
    bf16x8 kf0 = {}, kf1 = {};
    if (quad < 2) {
      int mc0 = m0 + col < LL ? m0 + col : LL - 1;
      int mc1 = m0 + 16 + col < LL ? m0 + 16 + col : LL - 1;
      kf0 = *reinterpret_cast<const bf16x8*>(&kp[mc0 * 16 + quad * 8]);
      kf1 = *reinterpret_cast<const bf16x8*>(&kp[mc1 * 16 + quad * 8]);
    }
    bf16x8 vf;
    {
      int ms = m0 + quad * 8; if (ms > LL - 8) ms = LL - 8;
      vf = *reinterpret_cast<const bf16x8*>(&vp[col * LL + ms]);
    }
    const float4 a4 = *reinterpret_cast<const float4*>(&mb[m0 + quad * 4]);
    const float4 b4 = *reinterpret_cast<const float4*>(&mb[m0 + 16 + quad * 4]);
    float madd[8] = {a4.x, a4.y, a4.z, a4.w, b4.x, b4.y, b4.z, b4.w};
    #pragma unroll
    for (int f = 0; f < 4; f++) {
      f32x4 z = {0.f, 0.f, 0.f, 0.f};
      f32x4 s0 = __builtin_amdgcn_mfma_f32_16x16x32_bf16(kf0, qf[f], z, 0, 0, 0);
      f32x4 s1 = __builtin_amdgcn_mfma_f32_16x16x32_bf16(kf1, qf[f], z, 0, 0, 0);
      float p[8];
      #pragma unroll
      for (int r = 0; r < 4; r++) {
        p[r]     = EXP2F(s0[r] * scale2 + madd[r]);
        p[4 + r] = EXP2F(s1[r] * scale2 + madd[4 + r]);
      }
      float ps = 0.f;
      #pragma unroll
      for (int i = 0; i < 8; i++) ps += p[i];
      psum[f] += ps;
      short* row = &Pl[w][f & 1][col * 40];
      short4 h0 = __builtin_bit_cast(short4, make_uint2(pkbf(p[1], p[0]), pkbf(p[3], p[2])));
      short4 h1 = __builtin_bit_cast(short4, make_uint2(pkbf(p[5], p[4]), pkbf(p[7], p[6])));
      *reinterpret_cast<short4*>(&row[quad * 4])      = h0;
      *reinterpret_cast<short4*>(&row[16 + quad * 4]) = h1;
      bf16x8 pf = *reinterpret_cast<const bf16x8*>(&Pl[w][f & 1][col * 40 + quad * 8]);
      of[f] = __builtin_amdgcn_mfma_f32_16x16x32_bf16(vf, pf, of[f], 0, 0, 0);
    }
  }
  // normalize + write attn output DIRECTLY into frag layout (c, l_local):
  // addr = (f*4 + (c>>5))*512 + ((c>>3)&3)*128 + (c&7) + col*8
  #pragma unroll
  for (int f = 0; f < 4; f++) {
    float s = psum[f];
    s += __shfl_xor(s, 16);
    s += __shfl_xor(s, 32);
    float inv = 1.f / s;
    if (l0 + f * 16 < LL) {
      #pragma unroll
      for (int r = 0; r < 4; r++) {
        int c = h * 16 + quad * 4 + r;
        short vv = f2bf(of[f][r] * inv);
        XsF[(f * 4 + (c >> 5)) * 512 + ((c >> 3) & 3) * 128 + (c & 7) + col * 8] = vv;
      }
    }
  }
  __syncthreads();

  // ---- WO GEMM (input = XsF frags, zero staging) ----
  int obase = w * 16;
  int wo_ = w * 16 + (lane & 15);
  int cb = (lane >> 4) * 8;
  {
    bf16x8 af[4];
    #pragma unroll
    for (int kt2 = 0; kt2 < 4; kt2++) {
      const float* wp = wo + wo_ * 128 + kt2 * 32 + cb;
      const float4 a0 = *reinterpret_cast<const float4*>(wp);
      const float4 a1 = *reinterpret_cast<const float4*>(wp + 4);
      bf16x8 v;
      v[0] = f2bf(a0.x); v[1] = f2bf(a0.y); v[2] = f2bf(a0.z); v[3] = f2bf(a0.w);
      v[4] = f2bf(a1.x); v[5] = f2bf(a1.y); v[6] = f2bf(a1.z); v[7] = f2bf(a1.w);
      af[kt2] = v;
    }
    f32x4 acc[4];
    #pragma unroll
    for (int lf = 0; lf < 4; lf++) acc[lf] = (f32x4){0.f, 0.f, 0.f, 0.f};
    #pragma unroll
    for (int kt2 = 0; kt2 < 4; kt2++) {
      #pragma unroll
      for (int lf = 0; lf < 4; lf++) {
        bf16x8 bx = *reinterpret_cast<const bf16x8*>(&XsF[(lf * 4 + kt2) * 512 + lane * 8]);
        acc[lf] = __builtin_amdgcn_mfma_f32_16x16x32_bf16(af[kt2], bx, acc[lf], 0, 0, 0);
      }
    }
    float bv4[4];
    #pragma unroll
    for (int r = 0; r < 4; r++) bv4[r] = bo[obase + quad * 4 + r];
    float lsum = 0.f, lsq = 0.f;
    #pragma unroll
    for (int lf = 0; lf < 4; lf++) {
      if (l0 + lf * 16 < LL) {
        int l = l0 + lf * 16 + col;
        #pragma unroll
        for (int r = 0; r < 4; r++) {
          int o = obase + quad * 4 + r;
          float v = acc[lf][r] + bv4[r];
          v += bf2f(r0[(size_t)bb * CL + (size_t)o * LL + l]);
          unsigned short hb = (unsigned short)f2bf(v);
          R1[o * 68 + lf * 16 + col] = (short)hb;
          float vf = bf2f(hb);
          lsum += vf; lsq += vf * vf;
        }
      }
    }
    #pragma unroll
    for (int off = 32; off > 0; off >>= 1) {
      lsum += __shfl_down(lsum, off);
      lsq  += __shfl_down(lsq, off);
    }
    if (lane == 0) { red[w * 2] = lsum; red[w * 2 + 1] = lsq; }
    __syncthreads();
    stats_pub(sx, 5, bb, jx, red, tid);
  }

  // ---- FC (LN from R1, GEMM, ReLU + resid -> out fp32) ----
  {
    float mu, rstd;
    stats_wait(sx, 5, bb, red, tid, mu, rstd);  // syncs: all waves done with XsF
    for (int idx = tid; idx < 1024; idx += 512) {
      int c = idx >> 3;
      int l8 = (idx & 7) * 8;
      bool valid = (l0 + l8) < LL;
      short hv[8];
      const ushort4 u0 = *reinterpret_cast<const ushort4*>(&R1[c * 68 + l8]);
      const ushort4 u1 = *reinterpret_cast<const ushort4*>(&R1[c * 68 + l8 + 4]);
      unsigned short uu[8] = {u0.x, u0.y, u0.z, u0.w, u1.x, u1.y, u1.z, u1.w};
      int col0c = valid ? (l0 + l8) : 0;
      const float* gp = lng + c * LL + col0c;
      const float* bp = lnb + c * LL + col0c;
      const float4 g0 = *reinterpret_cast<const float4*>(&gp[0]);
      const float4 g1 = *reinterpret_cast<const float4*>(&gp[4]);
      const float4 b0 = *reinterpret_cast<const float4*>(&bp[0]);
      const float4 b1 = *reinterpret_cast<const float4*>(&bp[4]);
      float gg[8] = {g0.x, g0.y, g0.z, g0.w, g1.x, g1.y, g1.z, g1.w};
      float bbv[8] = {b0.x, b0.y, b0.z, b0.w, b1.x, b1.y, b1.z, b1.w};
      #pragma unroll
      for (int e = 0; e < 8; e++) {
        float v = (bf2f(uu[e]) - mu) * rstd * gg[e] + bbv[e];
        hv[e] = valid ? f2bf(v) : (short)0;
      }
      int t = (l8 >> 4) * 4 + (c >> 5);
      int qd = (c >> 3) & 3;
      int j = c & 7;
      int base = t * 512 + qd * 128 + j;
      int colb = l8 & 15;
      #pragma unroll
      for (int e = 0; e < 8; e++) XsF[base + (colb + e) * 8] = hv[e];
    }
    __syncthreads();
    bf16x8 af[4];
    #pragma unroll
    for (int kt2 = 0; kt2 < 4; kt2++) {
      const float* wp = fcw + wo_ * 128 + kt2 * 32 + cb;
      const float4 a0 = *reinterpret_cast<const float4*>(wp);
      const float4 a1 = *reinterpret_cast<const float4*>(wp + 4);
      bf16x8 v;
      v[0] = f2bf(a0.x); v[1] = f2bf(a0.y); v[2] = f2bf(a0.z); v[3] = f2bf(a0.w);
      v[4] = f2bf(a1.x); v[5] = f2bf(a1.y); v[6] = f2bf(a1.z); v[7] = f2bf(a1.w);
      af[kt2] = v;
    }
    f32x4 acc[4];
    #pragma unroll
    for (int lf = 0; lf < 4; lf++) acc[lf] = (f32x4){0.f, 0.f, 0.f, 0.f};
    #pragma unroll
    for (int kt2 = 0; kt2 < 4; kt2++) {
      #pragma unroll
      for (int lf = 0; lf < 4; lf++) {
        bf16x8 bx = *reinterpret_cast<const bf16x8*>(&XsF[(lf * 4 + kt2) * 512 + lane * 8]);
        acc[lf] = __builtin_amdgcn_mfma_f32_16x16x32_bf16(af[kt2], bx, acc[lf], 0, 0, 0);
      }
    }
    float bv4[4];
    #pragma unroll
    for (int r = 0; r < 4; r++) bv4[r] = fcb[obase + quad * 4 + r];
    #pragma unroll
    for (int lf = 0; lf < 4; lf++) {
      if (l0 + lf * 16 < LL) {
        int l = l0 + lf * 16 + col;
        #pragma unroll
        for (int r = 0; r < 4; r++) {
          int o = obase + quad * 4 + r;
          float v = acc[lf][r] + bv4[r];
          v = fmaxf(v, 0.f);
          v += bf2f((unsigned short)R1[o * 68 + lf * 16 + col]);
          out[(size_t)bb * CL + (size_t)o * LL + l] = v;
        }
      }
    }
  }
}

// ---------------------------------------------------------------------------
extern "C" void kernel_launch(void* const* d_in, const int* in_sizes, int n_in,
                              void* d_out, int out_size, void* d_ws, size_t ws_size,
                              hipStream_t stream) {
  const float* x    = (const float*)d_in[0];
  const float* mask = (const float*)d_in[1];
  const float* dw_w = (const float*)d_in[2];
  const float* dw_b = (const float*)d_in[3];
  const float* pw_w = (const float*)d_in[4];
  const float* pw_b = (const float*)d_in[5];
  const float* wq   = (const float*)d_in[6];
  const float* bq   = (const float*)d_in[7];
  const float* wk   = (const float*)d_in[8];
  const float* bk   = (const float*)d_in[9];
  const float* wvp  = (const float*)d_in[10];
  const float* bv   = (const float*)d_in[11];
  const float* wo   = (const float*)d_in[12];
  const float* bo   = (const float*)d_in[13];
  const float* fcw  = (const float*)d_in[14];
  const float* fcb  = (const float*)d_in[15];
  const float* lng  = (const float*)d_in[16];
  const float* lnb  = (const float*)d_in[17];
  float* out = (float*)d_out;
  float* ws  = (float*)d_ws;

  float* sx    = ws;                                    // 6*64*32 f atomics
  float* maddb = ws + 6 * 64 * 32;                      // 64*416 f
  unsigned short* r0 = (unsigned short*)(maddb + 64 * 416);
  unsigned short* qt = r0 + NBCL;
  unsigned short* kt = qt + NBCL;
  unsigned short* vbf = kt + NBCL;

  hipMemsetAsync(sx, 0, 6 * 64 * 32 * sizeof(float), stream);

  fused_main<<<dim3(7, BN), 512, 0, stream>>>(
      pw_w, wq, wk, wvp, pw_b, dw_b, mask, x, lng, lnb, dw_w,
      bq, bk, bv, sx, maddb, r0, qt, kt, vbf);
  attn_wo_fc<<<dim3(7, BN), 512, 0, stream>>>(
      qt, kt, vbf, maddb, r0, wo, fcw, bo, fcb, lng, lnb, sx, out);
}